// Round 1
// baseline (4894.869 us; speedup 1.0000x reference)
//
#include <hip/hip_runtime.h>
#include <hip/hip_bf16.h>

// Problem constants
static constexpr int kB      = 4;
static constexpr int kT      = 1024;
static constexpr int kDIN    = 8;
static constexpr int kDMODEL = 512;
static constexpr int kNLAYER = 2;
static constexpr int kHOR    = 24;
static constexpr int kDOUT   = 8;
static constexpr int kDSTATE = 64;
static constexpr int kDCONV  = 4;
static constexpr int kDINNER = 1024;   // EXPAND * D_MODEL
static constexpr int kDTRANK = 32;     // ceil(512/16)
static constexpr int kXPROJ  = kDTRANK + 2 * kDSTATE; // 160
static constexpr int kBT     = kB * kT;               // 4096

__device__ __forceinline__ float silu_f(float x)     { return x / (1.f + __expf(-x)); }
__device__ __forceinline__ float softplus_f(float x) { return (x > 20.f) ? x : log1pf(__expf(x)); }
__device__ __forceinline__ float gelu_f(float x)     { return 0.5f * x * (1.f + erff(x * 0.70710678118654752f)); }

// ---------------------------------------------------------------------------
// Generic naive GEMM: C[m,n] = act(sum_k A[m,k]*B[k,n] + bias[n])
// One thread per output column n; MROWS rows per thread (A loads are
// block-uniform -> scalar loads; B loads coalesced across lanes, reused
// across the MROWS accumulators).
// ACT: 0=none, 1=silu, 2=softplus, 3=gelu
// ---------------------------------------------------------------------------
template<int MROWS, int ACT>
__global__ __launch_bounds__(256) void gemm_kernel(
    const float* __restrict__ A, int lda,
    const float* __restrict__ B, int ldb,
    const float* __restrict__ bias,
    float* __restrict__ C, int ldc,
    int N, int K)
{
    int n  = blockIdx.x * 256 + threadIdx.x;
    int m0 = blockIdx.y * MROWS;
    if (n >= N) return;

    const float* a  = A + (size_t)m0 * lda;
    const float* bp = B + n;

    float acc[MROWS];
#pragma unroll
    for (int r = 0; r < MROWS; ++r) acc[r] = 0.f;

    for (int k = 0; k < K; ++k) {
        float bv = bp[(size_t)k * ldb];
#pragma unroll
        for (int r = 0; r < MROWS; ++r)
            acc[r] = fmaf(a[r * lda + k], bv, acc[r]);
    }

    float bb = bias ? bias[n] : 0.f;
#pragma unroll
    for (int r = 0; r < MROWS; ++r) {
        float v = acc[r] + bb;
        if      (ACT == 1) v = silu_f(v);
        else if (ACT == 2) v = softplus_f(v);
        else if (ACT == 3) v = gelu_f(v);
        C[(size_t)(m0 + r) * ldc + n] = v;
    }
}

// ---------------------------------------------------------------------------
// Depthwise causal conv (width 4) + bias + SiLU.
// xb layout: (b*T + t, d) row-major. One thread per (b,t,d).
// ---------------------------------------------------------------------------
__global__ __launch_bounds__(256) void conv_silu_kernel(
    const float* __restrict__ xb,
    const float* __restrict__ cw,   // (D_INNER, 4)
    const float* __restrict__ cb,   // (D_INNER,)
    float* __restrict__ xc)
{
    int idx = blockIdx.x * 256 + threadIdx.x;      // over B*T*D_INNER
    int d   = idx & (kDINNER - 1);
    int bt  = idx >> 10;                           // b*T + t
    int t   = bt & (kT - 1);

    float4 w = *reinterpret_cast<const float4*>(cw + d * 4);
    float acc = cb[d];

    const float* base = xb + (size_t)bt * kDINNER + d;
    if (t >= 3) {
        acc = fmaf(base[-3 * kDINNER], w.x, acc);
        acc = fmaf(base[-2 * kDINNER], w.y, acc);
        acc = fmaf(base[-1 * kDINNER], w.z, acc);
        acc = fmaf(base[0],            w.w, acc);
    } else {
        if (t >= 3) acc = fmaf(base[-3 * kDINNER], w.x, acc);
        if (t >= 2) acc = fmaf(base[-2 * kDINNER], w.y, acc);
        if (t >= 1) acc = fmaf(base[-1 * kDINNER], w.z, acc);
        acc = fmaf(base[0], w.w, acc);
    }
    xc[idx] = silu_f(acc);
}

// ---------------------------------------------------------------------------
// Selective scan, one 64-lane wave per (b, d). Lane n holds state n.
// Fused gating epilogue: yg = (y + Dsk[d]*xc) * silu_z   (z pre-silu'd).
// ---------------------------------------------------------------------------
__global__ __launch_bounds__(256) void scan_kernel(
    const float* __restrict__ dt,    // (b*T+t, d)
    const float* __restrict__ xdb,   // (b*T+t, 160): [0:32) dtr, [32:96) B, [96:160) C
    const float* __restrict__ xc,    // (b*T+t, d)
    const float* __restrict__ zs,    // silu(z), (b*T+t, d)
    const float* __restrict__ Alog,  // (d, 64)
    const float* __restrict__ Dsk,   // (d,)
    float* __restrict__ yg)          // (b*T+t, d)
{
    int gw   = (blockIdx.x * 256 + threadIdx.x) >> 6;  // global wave = b*1024 + d
    int lane = threadIdx.x & 63;
    int b    = gw >> 10;
    int d    = gw & (kDINNER - 1);

    float a   = -__expf(Alog[d * kDSTATE + lane]);
    float dsk = Dsk[d];
    float s   = 0.f;

    const float* dtp = dt  + (size_t)(b * kT) * kDINNER + d;
    const float* xcp = xc  + (size_t)(b * kT) * kDINNER + d;
    const float* zp  = zs  + (size_t)(b * kT) * kDINNER + d;
    const float* bp  = xdb + (size_t)(b * kT) * kXPROJ + kDTRANK + lane;
    const float* cp  = bp + kDSTATE;
    float*       yp  = yg  + (size_t)(b * kT) * kDINNER + d;

    for (int t = 0; t < kT; ++t) {
        float dtv = *dtp;  dtp += kDINNER;
        float xv  = *xcp;  xcp += kDINNER;
        float Bv  = *bp;   bp  += kXPROJ;
        float Cv  = *cp;   cp  += kXPROJ;

        float dA = __expf(dtv * a);
        s = fmaf(dA, s, dtv * Bv * xv);

        float y = s * Cv;
#pragma unroll
        for (int m = 32; m >= 1; m >>= 1)
            y += __shfl_xor(y, m, 64);

        if (lane == 0) {
            float zv = *zp;
            *yp = (y + dsk * xv) * zv;
        }
        zp += kDINNER;
        yp += kDINNER;
    }
}

// ---------------------------------------------------------------------------
// LayerNorm of the 4 last-token rows only.
// ---------------------------------------------------------------------------
__global__ __launch_bounds__(256) void ln_last_kernel(
    const float* __restrict__ h,    // (b*T+t, 512)
    const float* __restrict__ g,
    const float* __restrict__ be,
    float* __restrict__ out)        // (b, 512)
{
    __shared__ float sbuf[8];
    int b = blockIdx.x, tid = threadIdx.x;
    const float* row = h + (size_t)(b * kT + (kT - 1)) * kDMODEL;

    float v0 = row[tid], v1 = row[tid + 256];
    float s = v0 + v1;
    float q = v0 * v0 + v1 * v1;
#pragma unroll
    for (int m = 32; m >= 1; m >>= 1) {
        s += __shfl_xor(s, m, 64);
        q += __shfl_xor(q, m, 64);
    }
    int wid = tid >> 6;
    if ((tid & 63) == 0) { sbuf[wid] = s; sbuf[4 + wid] = q; }
    __syncthreads();
    if (tid == 0) {
        float S = 0.f, Q = 0.f;
        for (int i = 0; i < 4; ++i) { S += sbuf[i]; Q += sbuf[4 + i]; }
        sbuf[0] = S; sbuf[4] = Q;
    }
    __syncthreads();
    float mean = sbuf[0] * (1.f / kDMODEL);
    float var  = sbuf[4] * (1.f / kDMODEL) - mean * mean;
    float inv  = rsqrtf(var + 1e-5f);

    out[b * kDMODEL + tid]       = (v0 - mean) * inv * g[tid]       + be[tid];
    out[b * kDMODEL + tid + 256] = (v1 - mean) * inv * g[tid + 256] + be[tid + 256];
}

// ---------------------------------------------------------------------------
extern "C" void kernel_launch(void* const* d_in, const int* in_sizes, int n_in,
                              void* d_out, int out_size, void* d_ws, size_t ws_size,
                              hipStream_t stream)
{
    const float* x      = (const float*)d_in[0];   // (4,1024,8)
    const float* W_in   = (const float*)d_in[1];   // (8,512)
    const float* b_in   = (const float*)d_in[2];   // (512,)
    const float* W_xz   = (const float*)d_in[3];   // (2,512,2048)
    const float* conv_w = (const float*)d_in[4];   // (2,1024,4)
    const float* conv_b = (const float*)d_in[5];   // (2,1024)
    const float* W_xp   = (const float*)d_in[6];   // (2,1024,160)
    const float* W_dt   = (const float*)d_in[7];   // (2,32,1024)
    const float* b_dt   = (const float*)d_in[8];   // (2,1024)
    const float* A_log  = (const float*)d_in[9];   // (2,1024,64)
    const float* D_skip = (const float*)d_in[10];  // (2,1024)
    const float* W_out  = (const float*)d_in[11];  // (2,1024,512)
    const float* ln_g   = (const float*)d_in[12];
    const float* ln_b   = (const float*)d_in[13];
    const float* W_h1   = (const float*)d_in[14];  // (512,512)
    const float* b_h1   = (const float*)d_in[15];
    const float* W_h2   = (const float*)d_in[16];  // (512,192)
    const float* b_h2   = (const float*)d_in[17];
    float* out = (float*)d_out;                    // (4,24,8) = 768 f32

    // Workspace layout (floats). Total ~78.1 MB.
    float* ws  = (float*)d_ws;
    float* h   = ws;                         // 4096*512
    float* xb  = h   + kBT * kDMODEL;        // 4096*1024  (reused for dt after conv)
    float* z   = xb  + kBT * kDINNER;        // 4096*1024  (stores silu(z))
    float* xc  = z   + kBT * kDINNER;        // 4096*1024
    float* ys  = xc  + kBT * kDINNER;        // 4096*1024  (gated output)
    float* xdb = ys  + kBT * kDINNER;        // 4096*160
    float* ln  = xdb + kBT * kXPROJ;         // 4*512
    float* hid = ln  + kB * kDMODEL;         // 4*512
    float* dt  = xb;                         // reuse xb region after conv

    // 1. h = x @ W_in + b_in            (4096 x 512, K=8)
    gemm_kernel<8, 0><<<dim3(2, kBT / 8), 256, 0, stream>>>(
        x, kDIN, W_in, kDMODEL, b_in, h, kDMODEL, kDMODEL, kDIN);

    for (int l = 0; l < kNLAYER; ++l) {
        const float* Wxz_l = W_xz   + (size_t)l * kDMODEL * 2 * kDINNER;
        const float* cw_l  = conv_w + (size_t)l * kDINNER * kDCONV;
        const float* cb_l  = conv_b + (size_t)l * kDINNER;
        const float* Wxp_l = W_xp   + (size_t)l * kDINNER * kXPROJ;
        const float* Wdt_l = W_dt   + (size_t)l * kDTRANK * kDINNER;
        const float* bdt_l = b_dt   + (size_t)l * kDINNER;
        const float* Al_l  = A_log  + (size_t)l * kDINNER * kDSTATE;
        const float* Dsk_l = D_skip + (size_t)l * kDINNER;
        const float* Wo_l  = W_out  + (size_t)l * kDINNER * kDMODEL;

        // 2a. xb = h @ W_xz[:, :1024]   (4096 x 1024, K=512)
        gemm_kernel<8, 0><<<dim3(4, kBT / 8), 256, 0, stream>>>(
            h, kDMODEL, Wxz_l, 2 * kDINNER, nullptr, xb, kDINNER, kDINNER, kDMODEL);
        // 2b. z = silu(h @ W_xz[:, 1024:])
        gemm_kernel<8, 1><<<dim3(4, kBT / 8), 256, 0, stream>>>(
            h, kDMODEL, Wxz_l + kDINNER, 2 * kDINNER, nullptr, z, kDINNER, kDINNER, kDMODEL);
        // 2c. xc = silu(causal_conv(xb) + cb)
        conv_silu_kernel<<<(kBT * kDINNER) / 256, 256, 0, stream>>>(xb, cw_l, cb_l, xc);
        // 2d. xdb = xc @ W_xproj        (4096 x 160, K=1024)
        gemm_kernel<8, 0><<<dim3(1, kBT / 8), 256, 0, stream>>>(
            xc, kDINNER, Wxp_l, kXPROJ, nullptr, xdb, kXPROJ, kXPROJ, kDINNER);
        // 2e. dt = softplus(xdb[:, :32] @ W_dt + b_dt)   (4096 x 1024, K=32)
        gemm_kernel<8, 2><<<dim3(4, kBT / 8), 256, 0, stream>>>(
            xdb, kXPROJ, Wdt_l, kDINNER, bdt_l, dt, kDINNER, kDINNER, kDTRANK);
        // 2f. scan + gate: ys = (scan_y + Dsk*xc) * silu_z
        scan_kernel<<<(kB * kDINNER * 64) / 256, 256, 0, stream>>>(
            dt, xdb, xc, z, Al_l, Dsk_l, ys);
        // 2g. h = ys @ W_out            (4096 x 512, K=1024)
        gemm_kernel<8, 0><<<dim3(2, kBT / 8), 256, 0, stream>>>(
            ys, kDINNER, Wo_l, kDMODEL, nullptr, h, kDMODEL, kDMODEL, kDINNER);
    }

    // 3. LayerNorm of last-token rows
    ln_last_kernel<<<kB, 256, 0, stream>>>(h, ln_g, ln_b, ln);
    // 4. hid = gelu(ln @ W_h1 + b_h1)   (4 x 512, K=512)
    gemm_kernel<4, 3><<<dim3(2, 1), 256, 0, stream>>>(
        ln, kDMODEL, W_h1, kDMODEL, b_h1, hid, kDMODEL, kDMODEL, kDMODEL);
    // 5. out = hid @ W_h2 + b_h2        (4 x 192, K=512)
    gemm_kernel<4, 0><<<dim3(1, 1), 256, 0, stream>>>(
        hid, kDMODEL, W_h2, kHOR * kDOUT, b_h2, out, kHOR * kDOUT, kHOR * kDOUT, kDMODEL);
}

// Round 2
// 1271.655 us; speedup vs baseline: 3.8492x; 3.8492x over previous
//
#include <hip/hip_runtime.h>
#include <hip/hip_bf16.h>

// Problem constants
static constexpr int kB      = 4;
static constexpr int kT      = 1024;
static constexpr int kDIN    = 8;
static constexpr int kDMODEL = 512;
static constexpr int kNLAYER = 2;
static constexpr int kHOR    = 24;
static constexpr int kDOUT   = 8;
static constexpr int kDSTATE = 64;
static constexpr int kDINNER = 1024;
static constexpr int kDTRANK = 32;
static constexpr int kXPROJ  = 160;          // 32 + 64 + 64
static constexpr int kXPAD   = 256;          // padded xdb row stride
static constexpr int kBT     = kB * kT;      // 4096

typedef __bf16 bf16x8 __attribute__((ext_vector_type(8)));
typedef float  f32x4  __attribute__((ext_vector_type(4)));

__device__ __forceinline__ float silu_f(float x)     { return x / (1.f + __expf(-x)); }
__device__ __forceinline__ float softplus_f(float x) { return (x > 20.f) ? x : log1pf(__expf(x)); }
__device__ __forceinline__ float gelu_f(float x)     { return 0.5f * x * (1.f + erff(x * 0.70710678118654752f)); }

// ---------------------------------------------------------------------------
// Weight transpose + f32->bf16 convert:  out[n][k] = bf16(in[k][n]), zero-pad.
// 32x32 LDS tile; coalesced read and write.
// ---------------------------------------------------------------------------
__global__ __launch_bounds__(256) void wtrans_kernel(
    const float* __restrict__ in, int K, int N,
    __hip_bfloat16* __restrict__ out, int Kpad, int Npad)
{
    __shared__ float tile[32][33];
    const int tid = threadIdx.x;
    const int n0 = blockIdx.x * 32;
    const int k0 = blockIdx.y * 32;

#pragma unroll
    for (int p = 0; p < 4; ++p) {
        int idx = p * 256 + tid;
        int ki = idx >> 5, ni = idx & 31;
        float v = 0.f;
        if (k0 + ki < K && n0 + ni < N) v = in[(size_t)(k0 + ki) * N + n0 + ni];
        tile[ki][ni] = v;
    }
    __syncthreads();
#pragma unroll
    for (int p = 0; p < 4; ++p) {
        int idx = p * 256 + tid;
        int ni = idx >> 5, ki = idx & 31;
        out[(size_t)(n0 + ni) * Kpad + k0 + ki] = __float2bfloat16(tile[ki][ni]);
    }
}

// ---------------------------------------------------------------------------
// MFMA bf16 GEMM, B-transposed:  C[m][n] = epilogue( sum_k A[m][k]*BT[n][k] )
// 128x128 tile, BK=64, 256 threads (4 waves, 2x2), each wave 64x64 (4x4 frags
// of 16x16x32). Single-buffered LDS, 2 barriers per K-step.
// MODE 0: XZ split  (col<1024 -> f32 C=xb ; col>=1024 -> bf16 silu -> C2=z)
// MODE 1: plain     (f32 C + bf16 C2)
// MODE 2: dt        (softplus(v + bias[col]) -> f32 C)
// ---------------------------------------------------------------------------
template<int MODE>
__global__ __launch_bounds__(256) void mfma_gemm_bt(
    const __hip_bfloat16* __restrict__ A, int lda,
    const __hip_bfloat16* __restrict__ BT, int ldb,
    const float* __restrict__ bias,
    float* __restrict__ C, int ldc,
    void* __restrict__ C2,
    int K)
{
    __shared__ __align__(16) __hip_bfloat16 sA[128][64];
    __shared__ __align__(16) __hip_bfloat16 sB[128][64];

    const int tid  = threadIdx.x;
    const int lane = tid & 63;
    const int w    = tid >> 6;
    const int wm   = w >> 1, wn = w & 1;
    const int m0   = blockIdx.y * 128;
    const int n0   = blockIdx.x * 128;

    f32x4 acc[4][4] = {};

    const int lrow = lane & 15;
    const int lk   = (lane >> 4) << 3;      // 0,8,16,24 (contiguous-8 k per lane)

    const int srow = tid >> 3;               // staging: 32 rows/pass
    const int scol = (tid & 7) * 8;          // 16B chunks

    for (int k0 = 0; k0 < K; k0 += 64) {
        __syncthreads();
#pragma unroll
        for (int p = 0; p < 4; ++p) {
            int r = srow + p * 32;
            *reinterpret_cast<uint4*>(&sA[r][scol]) =
                *reinterpret_cast<const uint4*>(A + (size_t)(m0 + r) * lda + k0 + scol);
            *reinterpret_cast<uint4*>(&sB[r][scol]) =
                *reinterpret_cast<const uint4*>(BT + (size_t)(n0 + r) * ldb + k0 + scol);
        }
        __syncthreads();
#pragma unroll
        for (int ks = 0; ks < 2; ++ks) {
            bf16x8 af[4], bfr[4];
#pragma unroll
            for (int i = 0; i < 4; ++i) {
                af[i]  = *reinterpret_cast<const bf16x8*>(&sA[wm * 64 + i * 16 + lrow][ks * 32 + lk]);
                bfr[i] = *reinterpret_cast<const bf16x8*>(&sB[wn * 64 + i * 16 + lrow][ks * 32 + lk]);
            }
#pragma unroll
            for (int i = 0; i < 4; ++i)
#pragma unroll
                for (int j = 0; j < 4; ++j)
                    acc[i][j] = __builtin_amdgcn_mfma_f32_16x16x32_bf16(af[i], bfr[j], acc[i][j], 0, 0, 0);
        }
    }

    const int crow = (lane >> 4) * 4;
    const int ccol = lane & 15;
#pragma unroll
    for (int i = 0; i < 4; ++i) {
#pragma unroll
        for (int j = 0; j < 4; ++j) {
#pragma unroll
            for (int r = 0; r < 4; ++r) {
                int row = m0 + wm * 64 + i * 16 + crow + r;
                int col = n0 + wn * 64 + j * 16 + ccol;
                float v = acc[i][j][r];
                if (MODE == 0) {
                    if (col < kDINNER)
                        C[(size_t)row * ldc + col] = v;
                    else
                        ((__hip_bfloat16*)C2)[(size_t)row * ldc + (col - kDINNER)] =
                            __float2bfloat16(silu_f(v));
                } else if (MODE == 1) {
                    C[(size_t)row * ldc + col] = v;
                    ((__hip_bfloat16*)C2)[(size_t)row * ldc + col] = __float2bfloat16(v);
                } else {
                    C[(size_t)row * ldc + col] = softplus_f(v + bias[col]);
                }
            }
        }
    }
}

// ---------------------------------------------------------------------------
// Input projection: h = x @ W_in + b_in  (K=8), writes f32 + bf16.
// ---------------------------------------------------------------------------
__global__ __launch_bounds__(256) void in_proj_kernel(
    const float* __restrict__ x, const float* __restrict__ W,
    const float* __restrict__ b,
    float* __restrict__ h, __hip_bfloat16* __restrict__ hb)
{
    int idx = blockIdx.x * 256 + threadIdx.x;       // over 4096*512
    int m = idx >> 9, n = idx & 511;
    float acc = b[n];
    const float* xr = x + m * kDIN;
#pragma unroll
    for (int k = 0; k < kDIN; ++k)
        acc = fmaf(xr[k], W[k * kDMODEL + n], acc);
    h[idx]  = acc;
    hb[idx] = __float2bfloat16(acc);
}

// ---------------------------------------------------------------------------
// Depthwise causal conv (width 4) + bias + SiLU -> bf16.
// ---------------------------------------------------------------------------
__global__ __launch_bounds__(256) void conv_silu_kernel(
    const float* __restrict__ xb,
    const float* __restrict__ cw, const float* __restrict__ cb,
    __hip_bfloat16* __restrict__ xc)
{
    int idx = blockIdx.x * 256 + threadIdx.x;      // over B*T*D_INNER
    int d   = idx & (kDINNER - 1);
    int bt  = idx >> 10;
    int t   = bt & (kT - 1);

    float4 wv = *reinterpret_cast<const float4*>(cw + d * 4);
    float acc = cb[d];
    const float* base = xb + (size_t)bt * kDINNER + d;
    if (t >= 3) {
        acc = fmaf(base[-3 * kDINNER], wv.x, acc);
        acc = fmaf(base[-2 * kDINNER], wv.y, acc);
        acc = fmaf(base[-1 * kDINNER], wv.z, acc);
        acc = fmaf(base[0],            wv.w, acc);
    } else {
        if (t >= 2) acc = fmaf(base[-2 * kDINNER], wv.y, acc);
        if (t >= 1) acc = fmaf(base[-1 * kDINNER], wv.z, acc);
        acc = fmaf(base[0], wv.w, acc);
    }
    xc[idx] = __float2bfloat16(silu_f(acc));
}

// ---------------------------------------------------------------------------
// Selective scan, LDS-chunked. Block = 4 waves, same b, d = d0..d0+3.
// Lane n holds state n. Chunk of 64 timesteps staged in LDS.
// ---------------------------------------------------------------------------
__global__ __launch_bounds__(256) void scan_kernel(
    const float* __restrict__ dt,            // (bt,1024) f32
    const float* __restrict__ xdb,           // (bt,256)  f32: [32:96)=B [96:160)=C
    const __hip_bfloat16* __restrict__ xc,   // (bt,1024)
    const __hip_bfloat16* __restrict__ zs,   // (bt,1024) silu(z)
    const float* __restrict__ Alog,          // (1024,64)
    const float* __restrict__ Dsk,           // (1024,)
    __hip_bfloat16* __restrict__ yg)         // (bt,1024)
{
    __shared__ float sBC[64][128];
    __shared__ float sDt[64][4];
    __shared__ float sXc[64][4];
    __shared__ float sZ [64][4];
    __shared__ float sY [64][4];

    const int tid  = threadIdx.x;
    const int lane = tid & 63;
    const int w    = tid >> 6;
    const int bb   = blockIdx.x;
    const int b    = bb >> 8;
    const int d0   = (bb & 255) * 4;
    const int d    = d0 + w;

    const float a   = -__expf(Alog[d * kDSTATE + lane]);
    const float dsk = Dsk[d];
    float s = 0.f;

    const size_t rowbase = (size_t)b * kT;
    const int sr = tid >> 2, sj = tid & 3;

    for (int c = 0; c < kT / 64; ++c) {
        const int t0 = c * 64;
        __syncthreads();
        // stage B/C: 64 rows x 128 floats
#pragma unroll
        for (int p = 0; p < 8; ++p) {
            int idx = tid + p * 256;            // 0..2047 float4 index
            int r = idx >> 5, c4 = idx & 31;
            float4 v = *reinterpret_cast<const float4*>(
                xdb + (rowbase + t0 + r) * kXPAD + kDTRANK + c4 * 4);
            *reinterpret_cast<float4*>(&sBC[r][c4 * 4]) = v;
        }
        sDt[sr][sj] = dt[(rowbase + t0 + sr) * kDINNER + d0 + sj];
        sXc[sr][sj] = __bfloat162float(xc[(rowbase + t0 + sr) * kDINNER + d0 + sj]);
        sZ [sr][sj] = __bfloat162float(zs[(rowbase + t0 + sr) * kDINNER + d0 + sj]);
        __syncthreads();

#pragma unroll 4
        for (int i = 0; i < 64; ++i) {
            float Bv  = sBC[i][lane];
            float Cv  = sBC[i][64 + lane];
            float dtv = sDt[i][w];
            float xv  = sXc[i][w];
            float dA  = __expf(dtv * a);
            s = fmaf(dA, s, Bv * (dtv * xv));
            float y = s * Cv;
#pragma unroll
            for (int m = 32; m >= 1; m >>= 1)
                y += __shfl_xor(y, m, 64);
            if (lane == 0)
                sY[i][w] = (y + dsk * xv) * sZ[i][w];
        }
        __syncthreads();
        yg[(rowbase + t0 + sr) * kDINNER + d0 + sj] = __float2bfloat16(sY[sr][sj]);
    }
}

// ---------------------------------------------------------------------------
// Naive f32 GEMM (head only): C[m,n] = act(sum_k A[m,k]*B[k,n] + bias[n])
// ---------------------------------------------------------------------------
template<int MROWS, int ACT>
__global__ __launch_bounds__(256) void gemm_kernel(
    const float* __restrict__ A, int lda,
    const float* __restrict__ B, int ldb,
    const float* __restrict__ bias,
    float* __restrict__ C, int ldc,
    int N, int K)
{
    int n  = blockIdx.x * 256 + threadIdx.x;
    int m0 = blockIdx.y * MROWS;
    if (n >= N) return;
    const float* a  = A + (size_t)m0 * lda;
    const float* bp = B + n;
    float acc[MROWS];
#pragma unroll
    for (int r = 0; r < MROWS; ++r) acc[r] = 0.f;
    for (int k = 0; k < K; ++k) {
        float bv = bp[(size_t)k * ldb];
#pragma unroll
        for (int r = 0; r < MROWS; ++r)
            acc[r] = fmaf(a[r * lda + k], bv, acc[r]);
    }
    float bb = bias ? bias[n] : 0.f;
#pragma unroll
    for (int r = 0; r < MROWS; ++r) {
        float v = acc[r] + bb;
        if (ACT == 3) v = gelu_f(v);
        C[(size_t)(m0 + r) * ldc + n] = v;
    }
}

// ---------------------------------------------------------------------------
// LayerNorm of the 4 last-token rows only.
// ---------------------------------------------------------------------------
__global__ __launch_bounds__(256) void ln_last_kernel(
    const float* __restrict__ h,
    const float* __restrict__ g, const float* __restrict__ be,
    float* __restrict__ out)
{
    __shared__ float sbuf[8];
    int b = blockIdx.x, tid = threadIdx.x;
    const float* row = h + (size_t)(b * kT + (kT - 1)) * kDMODEL;

    float v0 = row[tid], v1 = row[tid + 256];
    float s = v0 + v1;
    float q = v0 * v0 + v1 * v1;
#pragma unroll
    for (int m = 32; m >= 1; m >>= 1) {
        s += __shfl_xor(s, m, 64);
        q += __shfl_xor(q, m, 64);
    }
    int wid = tid >> 6;
    if ((tid & 63) == 0) { sbuf[wid] = s; sbuf[4 + wid] = q; }
    __syncthreads();
    if (tid == 0) {
        float S = 0.f, Q = 0.f;
        for (int i = 0; i < 4; ++i) { S += sbuf[i]; Q += sbuf[4 + i]; }
        sbuf[0] = S; sbuf[4] = Q;
    }
    __syncthreads();
    float mean = sbuf[0] * (1.f / kDMODEL);
    float var  = sbuf[4] * (1.f / kDMODEL) - mean * mean;
    float inv  = rsqrtf(var + 1e-5f);
    out[b * kDMODEL + tid]       = (v0 - mean) * inv * g[tid]       + be[tid];
    out[b * kDMODEL + tid + 256] = (v1 - mean) * inv * g[tid + 256] + be[tid + 256];
}

// ---------------------------------------------------------------------------
extern "C" void kernel_launch(void* const* d_in, const int* in_sizes, int n_in,
                              void* d_out, int out_size, void* d_ws, size_t ws_size,
                              hipStream_t stream)
{
    const float* x      = (const float*)d_in[0];
    const float* W_in   = (const float*)d_in[1];
    const float* b_in   = (const float*)d_in[2];
    const float* W_xz   = (const float*)d_in[3];   // (2,512,2048)
    const float* conv_w = (const float*)d_in[4];
    const float* conv_b = (const float*)d_in[5];
    const float* W_xp   = (const float*)d_in[6];   // (2,1024,160)
    const float* W_dt   = (const float*)d_in[7];   // (2,32,1024)
    const float* b_dt   = (const float*)d_in[8];
    const float* A_log  = (const float*)d_in[9];
    const float* D_skip = (const float*)d_in[10];
    const float* W_out  = (const float*)d_in[11];  // (2,1024,512)
    const float* ln_g   = (const float*)d_in[12];
    const float* ln_b   = (const float*)d_in[13];
    const float* W_h1   = (const float*)d_in[14];
    const float* b_h1   = (const float*)d_in[15];
    const float* W_h2   = (const float*)d_in[16];
    const float* b_h2   = (const float*)d_in[17];
    float* out = (float*)d_out;

    // Workspace layout
    char* p = (char*)d_ws;
    auto alloc = [&](size_t bytes) { char* q = p; p += (bytes + 255) & ~(size_t)255; return q; };
    float*          h       = (float*)         alloc((size_t)kBT * kDMODEL * 4);   // 8 MB
    __hip_bfloat16* h_bf    = (__hip_bfloat16*)alloc((size_t)kBT * kDMODEL * 2);   // 4 MB
    float*          xb      = (float*)         alloc((size_t)kBT * kDINNER * 4);   // 16 MB (reused as dt)
    __hip_bfloat16* z_bf    = (__hip_bfloat16*)alloc((size_t)kBT * kDINNER * 2);   // 8 MB
    __hip_bfloat16* xc_bf   = (__hip_bfloat16*)alloc((size_t)kBT * kDINNER * 2);   // 8 MB
    float*          xdb     = (float*)         alloc((size_t)kBT * kXPAD * 4);     // 4 MB
    __hip_bfloat16* xdb_bf  = (__hip_bfloat16*)alloc((size_t)kBT * kXPAD * 2);     // 2 MB
    __hip_bfloat16* ys_bf   = (__hip_bfloat16*)alloc((size_t)kBT * kDINNER * 2);   // 8 MB
    __hip_bfloat16* wxz_bt  = (__hip_bfloat16*)alloc((size_t)2048 * 512 * 2);
    __hip_bfloat16* wxp_bt  = (__hip_bfloat16*)alloc((size_t)256 * 1024 * 2);
    __hip_bfloat16* wdt_bt  = (__hip_bfloat16*)alloc((size_t)1024 * 64 * 2);
    __hip_bfloat16* wout_bt = (__hip_bfloat16*)alloc((size_t)512 * 1024 * 2);
    float*          lnb     = (float*)         alloc(kB * kDMODEL * 4);
    float*          hid     = (float*)         alloc(kB * kDMODEL * 4);
    float*          dtb     = xb;   // dt reuses xb after conv

    // Input projection
    in_proj_kernel<<<(kBT * kDMODEL) / 256, 256, 0, stream>>>(x, W_in, b_in, h, h_bf);

    for (int l = 0; l < kNLAYER; ++l) {
        const float* Wxz_l = W_xz   + (size_t)l * kDMODEL * 2 * kDINNER;
        const float* cw_l  = conv_w + (size_t)l * kDINNER * 4;
        const float* cb_l  = conv_b + (size_t)l * kDINNER;
        const float* Wxp_l = W_xp   + (size_t)l * kDINNER * kXPROJ;
        const float* Wdt_l = W_dt   + (size_t)l * kDTRANK * kDINNER;
        const float* bdt_l = b_dt   + (size_t)l * kDINNER;
        const float* Al_l  = A_log  + (size_t)l * kDINNER * kDSTATE;
        const float* Dsk_l = D_skip + (size_t)l * kDINNER;
        const float* Wo_l  = W_out  + (size_t)l * kDINNER * kDMODEL;

        // Weight transposes (f32 -> bf16, N-major)
        wtrans_kernel<<<dim3(2048 / 32, 512 / 32),  256, 0, stream>>>(Wxz_l, 512,  2048, wxz_bt,  512,  2048);
        wtrans_kernel<<<dim3(256  / 32, 1024 / 32), 256, 0, stream>>>(Wxp_l, 1024, 160,  wxp_bt,  1024, 256);
        wtrans_kernel<<<dim3(1024 / 32, 64 / 32),   256, 0, stream>>>(Wdt_l, 32,   1024, wdt_bt,  64,   1024);
        wtrans_kernel<<<dim3(512  / 32, 1024 / 32), 256, 0, stream>>>(Wo_l,  1024, 512,  wout_bt, 1024, 512);

        // xz = h @ W_xz : xb (f32) + z (silu, bf16)
        mfma_gemm_bt<0><<<dim3(16, 32), 256, 0, stream>>>(
            h_bf, kDMODEL, wxz_bt, 512, nullptr, xb, kDINNER, z_bf, kDMODEL);
        // conv -> xc (bf16)
        conv_silu_kernel<<<(kBT * kDINNER) / 256, 256, 0, stream>>>(xb, cw_l, cb_l, xc_bf);
        // xdb = xc @ W_xproj  (f32 + bf16, ldc=256 padded)
        mfma_gemm_bt<1><<<dim3(2, 32), 256, 0, stream>>>(
            xc_bf, kDINNER, wxp_bt, 1024, nullptr, xdb, kXPAD, xdb_bf, kDINNER);
        // dt = softplus(xdb[:, :32] @ W_dt + b_dt)   (K padded to 64, BT zero-padded)
        mfma_gemm_bt<2><<<dim3(8, 32), 256, 0, stream>>>(
            xdb_bf, kXPAD, wdt_bt, 64, bdt_l, dtb, kDINNER, nullptr, 64);
        // scan + gate -> ys (bf16)
        scan_kernel<<<kB * kDINNER / 4, 256, 0, stream>>>(
            dtb, xdb, xc_bf, z_bf, Al_l, Dsk_l, ys_bf);
        // h = ys @ W_out  (f32 + bf16)
        mfma_gemm_bt<1><<<dim3(4, 32), 256, 0, stream>>>(
            ys_bf, kDINNER, wout_bt, 1024, nullptr, h, kDMODEL, h_bf, kDINNER);
    }

    // Tail: LN on last tokens + 2-layer head (tiny, f32)
    ln_last_kernel<<<kB, 256, 0, stream>>>(h, ln_g, ln_b, lnb);
    gemm_kernel<4, 3><<<dim3(2, 1), 256, 0, stream>>>(
        lnb, kDMODEL, W_h1, kDMODEL, b_h1, hid, kDMODEL, kDMODEL, kDMODEL);
    gemm_kernel<4, 0><<<dim3(1, 1), 256, 0, stream>>>(
        hid, kDMODEL, W_h2, kHOR * kDOUT, b_h2, out, kHOR * kDOUT, kHOR * kDOUT, kDMODEL);
}

// Round 4
// 826.302 us; speedup vs baseline: 5.9238x; 1.5390x over previous
//
#include <hip/hip_runtime.h>
#include <hip/hip_bf16.h>

// Problem constants
static constexpr int kB      = 4;
static constexpr int kT      = 1024;
static constexpr int kDIN    = 8;
static constexpr int kDMODEL = 512;
static constexpr int kNLAYER = 2;
static constexpr int kHOR    = 24;
static constexpr int kDOUT   = 8;
static constexpr int kDSTATE = 64;
static constexpr int kDINNER = 1024;
static constexpr int kDTRANK = 32;
static constexpr int kXPROJ  = 160;          // 32 + 64 + 64
static constexpr int kXPAD   = 256;          // padded xdb row stride
static constexpr int kBT     = kB * kT;      // 4096

typedef __bf16 bf16x8 __attribute__((ext_vector_type(8)));
typedef float  f32x4  __attribute__((ext_vector_type(4)));

__device__ __forceinline__ float silu_f(float x)     { return x / (1.f + __expf(-x)); }
__device__ __forceinline__ float softplus_f(float x) { return (x > 20.f) ? x : log1pf(__expf(x)); }
__device__ __forceinline__ float gelu_f(float x)     { return 0.5f * x * (1.f + erff(x * 0.70710678118654752f)); }

// Full-wave (64) f32 sum via DPP; result lands in lane 63. Pure VALU,
// no LDS pipe (replaces ~30-inst ds_bpermute shuffle chain).
// dpp_ctrl must be a compile-time constant -> template parameter.
template<int CTRL>
__device__ __forceinline__ float dpp_add_step(float y) {
    int t = __builtin_amdgcn_update_dpp(0, __float_as_int(y), CTRL, 0xf, 0xf, false);
    return y + __int_as_float(t);
}
__device__ __forceinline__ float wave_sum64_lane63(float y) {
    y = dpp_add_step<0x111>(y);  // row_shr:1
    y = dpp_add_step<0x112>(y);  // row_shr:2
    y = dpp_add_step<0x114>(y);  // row_shr:4
    y = dpp_add_step<0x118>(y);  // row_shr:8    -> lane15 of each row16 = row sum
    y = dpp_add_step<0x142>(y);  // row_bcast:15 -> lane31=r0+r1, lane63=r2+r3
    y = dpp_add_step<0x143>(y);  // row_bcast:31 -> lane63 = total
    return y;
}

// async global->LDS 16B
__device__ __forceinline__ void gld_lds16(const void* g, void* l) {
    __builtin_amdgcn_global_load_lds(
        (const __attribute__((address_space(1))) unsigned int*)g,
        (__attribute__((address_space(3))) unsigned int*)l, 16, 0, 0);
}

// ---------------------------------------------------------------------------
// Weight transpose + f32->bf16: out[n][k] = bf16(in[k][n]), zero-pad OOB.
// Batched over layers via blockIdx.z.
// ---------------------------------------------------------------------------
__global__ __launch_bounds__(256) void wtrans_kernel(
    const float* __restrict__ in, int K, int N, int in_lstride,
    __hip_bfloat16* __restrict__ out, int Kpad, int out_lstride)
{
    __shared__ float tile[32][33];
    const int tid = threadIdx.x;
    const int n0 = blockIdx.x * 32;
    const int k0 = blockIdx.y * 32;
    const float* inl = in + (size_t)blockIdx.z * in_lstride;
    __hip_bfloat16* outl = out + (size_t)blockIdx.z * out_lstride;

#pragma unroll
    for (int p = 0; p < 4; ++p) {
        int idx = p * 256 + tid;
        int ki = idx >> 5, ni = idx & 31;
        float v = 0.f;
        if (k0 + ki < K && n0 + ni < N) v = inl[(size_t)(k0 + ki) * N + n0 + ni];
        tile[ki][ni] = v;
    }
    __syncthreads();
#pragma unroll
    for (int p = 0; p < 4; ++p) {
        int idx = p * 256 + tid;
        int ni = idx >> 5, ki = idx & 31;
        outl[(size_t)(n0 + ni) * Kpad + k0 + ki] = __float2bfloat16(tile[ki][ni]);
    }
}

// ---------------------------------------------------------------------------
// MFMA bf16 GEMM, B-transposed. 128x128 tile, BK=64, 4 waves (2x2).
// Staging via global_load_lds width-16 (no VGPR round trip).
// MODE 0: XZ split (col<1024 -> f32 xb ; col>=1024 -> bf16 silu -> z)
// MODE 1: plain f32 C + bf16 C2
// MODE 2: softplus(v + bias[col]) -> f32 C
// ---------------------------------------------------------------------------
template<int MODE>
__global__ __launch_bounds__(256) void mfma_gemm_bt(
    const __hip_bfloat16* __restrict__ A, int lda,
    const __hip_bfloat16* __restrict__ BT, int ldb,
    const float* __restrict__ bias,
    float* __restrict__ C, int ldc,
    void* __restrict__ C2,
    int K)
{
    __shared__ __align__(16) __hip_bfloat16 sA[128][64];
    __shared__ __align__(16) __hip_bfloat16 sB[128][64];

    const int tid  = threadIdx.x;
    const int lane = tid & 63;
    const int w    = tid >> 6;
    const int wm   = w >> 1, wn = w & 1;
    const int m0   = blockIdx.y * 128;
    const int n0   = blockIdx.x * 128;

    f32x4 acc[4][4] = {};

    const int lrow = lane & 15;
    const int lk   = (lane >> 4) << 3;

    // staging geometry: thread tid -> row tid>>3, col (tid&7)*8 elements;
    // LDS dest = wave-uniform base + lane*16 (global_load_lds form)
    const int grow = tid >> 3;
    const int gcol = (tid & 7) * 8;
    char* ldsA = (char*)&sA[0][0] + w * 1024;
    char* ldsB = (char*)&sB[0][0] + w * 1024;

    for (int k0 = 0; k0 < K; k0 += 64) {
        __syncthreads();
#pragma unroll
        for (int p = 0; p < 4; ++p) {
            gld_lds16(A  + (size_t)(m0 + grow + p * 32) * lda + k0 + gcol, ldsA + p * 4096);
            gld_lds16(BT + (size_t)(n0 + grow + p * 32) * ldb + k0 + gcol, ldsB + p * 4096);
        }
        __syncthreads();
#pragma unroll
        for (int ks = 0; ks < 2; ++ks) {
            bf16x8 af[4], bfr[4];
#pragma unroll
            for (int i = 0; i < 4; ++i) {
                af[i]  = *reinterpret_cast<const bf16x8*>(&sA[wm * 64 + i * 16 + lrow][ks * 32 + lk]);
                bfr[i] = *reinterpret_cast<const bf16x8*>(&sB[wn * 64 + i * 16 + lrow][ks * 32 + lk]);
            }
#pragma unroll
            for (int i = 0; i < 4; ++i)
#pragma unroll
                for (int j = 0; j < 4; ++j)
                    acc[i][j] = __builtin_amdgcn_mfma_f32_16x16x32_bf16(af[i], bfr[j], acc[i][j], 0, 0, 0);
        }
    }

    const int crow = (lane >> 4) * 4;
    const int ccol = lane & 15;
#pragma unroll
    for (int i = 0; i < 4; ++i) {
#pragma unroll
        for (int j = 0; j < 4; ++j) {
#pragma unroll
            for (int r = 0; r < 4; ++r) {
                int row = m0 + wm * 64 + i * 16 + crow + r;
                int col = n0 + wn * 64 + j * 16 + ccol;
                float v = acc[i][j][r];
                if (MODE == 0) {
                    if (col < kDINNER)
                        C[(size_t)row * ldc + col] = v;
                    else
                        ((__hip_bfloat16*)C2)[(size_t)row * ldc + (col - kDINNER)] =
                            __float2bfloat16(silu_f(v));
                } else if (MODE == 1) {
                    C[(size_t)row * ldc + col] = v;
                    ((__hip_bfloat16*)C2)[(size_t)row * ldc + col] = __float2bfloat16(v);
                } else {
                    C[(size_t)row * ldc + col] = softplus_f(v + bias[col]);
                }
            }
        }
    }
}

// ---------------------------------------------------------------------------
// Input projection: h = x @ W_in + b_in  (K=8), writes f32 + bf16.
// ---------------------------------------------------------------------------
__global__ __launch_bounds__(256) void in_proj_kernel(
    const float* __restrict__ x, const float* __restrict__ W,
    const float* __restrict__ b,
    float* __restrict__ h, __hip_bfloat16* __restrict__ hb)
{
    int idx = blockIdx.x * 256 + threadIdx.x;
    int m = idx >> 9, n = idx & 511;
    float acc = b[n];
    const float* xr = x + m * kDIN;
#pragma unroll
    for (int k = 0; k < kDIN; ++k)
        acc = fmaf(xr[k], W[k * kDMODEL + n], acc);
    h[idx]  = acc;
    hb[idx] = __float2bfloat16(acc);
}

// ---------------------------------------------------------------------------
// Depthwise causal conv (width 4) + bias + SiLU -> bf16.
// ---------------------------------------------------------------------------
__global__ __launch_bounds__(256) void conv_silu_kernel(
    const float* __restrict__ xb,
    const float* __restrict__ cw, const float* __restrict__ cb,
    __hip_bfloat16* __restrict__ xc)
{
    int idx = blockIdx.x * 256 + threadIdx.x;
    int d   = idx & (kDINNER - 1);
    int bt  = idx >> 10;
    int t   = bt & (kT - 1);

    float4 wv = *reinterpret_cast<const float4*>(cw + d * 4);
    float acc = cb[d];
    const float* base = xb + (size_t)bt * kDINNER + d;
    if (t >= 3) {
        acc = fmaf(base[-3 * kDINNER], wv.x, acc);
        acc = fmaf(base[-2 * kDINNER], wv.y, acc);
        acc = fmaf(base[-1 * kDINNER], wv.z, acc);
        acc = fmaf(base[0],            wv.w, acc);
    } else {
        if (t >= 2) acc = fmaf(base[-2 * kDINNER], wv.y, acc);
        if (t >= 1) acc = fmaf(base[-1 * kDINNER], wv.z, acc);
        acc = fmaf(base[0], wv.w, acc);
    }
    xc[idx] = __float2bfloat16(silu_f(acc));
}

// ---------------------------------------------------------------------------
// Selective scan. Block = 4 waves (channels d0..d0+3, same b); lane = state n.
// 32-step chunks in LDS (~18 KB -> 8 blocks/CU, 32 waves/CU).
// Reduction via DPP (lane 63); z-gate applied at chunk write-out.
// ---------------------------------------------------------------------------
__global__ __launch_bounds__(256) void scan_kernel(
    const float* __restrict__ dt,            // (bt,1024) f32
    const float* __restrict__ xdb,           // (bt,256)  f32: [32:96)=B [96:160)=C
    const __hip_bfloat16* __restrict__ xc,   // (bt,1024)
    const __hip_bfloat16* __restrict__ zs,   // (bt,1024) silu(z)
    const float* __restrict__ Alog,          // (1024,64)
    const float* __restrict__ Dsk,           // (1024,)
    __hip_bfloat16* __restrict__ yg)         // (bt,1024)
{
    __shared__ float sBC[32][128];
    __shared__ float sDX[32][4][2];   // [t][w][0]=dt, [1]=xc
    __shared__ float sY [32][4];

    const int tid  = threadIdx.x;
    const int lane = tid & 63;
    const int w    = tid >> 6;
    const int bb   = blockIdx.x;
    const int b    = bb >> 8;
    const int d0   = (bb & 255) * 4;
    const int d    = d0 + w;

    const float a   = -__expf(Alog[d * kDSTATE + lane]);
    const float dsk = Dsk[d];
    float s = 0.f;
    const size_t rowbase = (size_t)b * kT;

    const int hr = (tid & 127) >> 2, hj = tid & 3, hs = tid >> 7;

    for (int c = 0; c < kT / 32; ++c) {
        const int t0 = c * 32;
        __syncthreads();
        // stage B/C: 32 rows x 128 f32
#pragma unroll
        for (int p = 0; p < 4; ++p) {
            int idx = tid + p * 256;
            int r = idx >> 5, c4 = idx & 31;
            *reinterpret_cast<float4*>(&sBC[r][c4 * 4]) =
                *reinterpret_cast<const float4*>(xdb + (rowbase + t0 + r) * kXPAD + kDTRANK + c4 * 4);
        }
        {
            size_t g = (rowbase + t0 + hr) * kDINNER + d0 + hj;
            if (hs == 0) sDX[hr][hj][0] = dt[g];
            else         sDX[hr][hj][1] = __bfloat162float(xc[g]);
        }
        __syncthreads();

#pragma unroll 8
        for (int i = 0; i < 32; ++i) {
            float Bv  = sBC[i][lane];
            float Cv  = sBC[i][64 + lane];
            float dtv = sDX[i][w][0];
            float xv  = sDX[i][w][1];
            float dA  = __expf(dtv * a);
            s = fmaf(dA, s, (dtv * xv) * Bv);
            float y = wave_sum64_lane63(s * Cv);
            if (lane == 63) sY[i][w] = fmaf(dsk, xv, y);
        }
        __syncthreads();
        if (tid < 128) {
            int r = tid >> 2, j = tid & 3;
            size_t g = (rowbase + t0 + r) * kDINNER + d0 + j;
            yg[g] = __float2bfloat16(sY[r][j] * __bfloat162float(zs[g]));
        }
    }
}

// ---------------------------------------------------------------------------
// Naive f32 GEMM (tiny head only).
// ---------------------------------------------------------------------------
template<int MROWS, int ACT>
__global__ __launch_bounds__(256) void gemm_kernel(
    const float* __restrict__ A, int lda,
    const float* __restrict__ B, int ldb,
    const float* __restrict__ bias,
    float* __restrict__ C, int ldc,
    int N, int K)
{
    int n  = blockIdx.x * 256 + threadIdx.x;
    int m0 = blockIdx.y * MROWS;
    if (n >= N) return;
    const float* a  = A + (size_t)m0 * lda;
    const float* bp = B + n;
    float acc[MROWS];
#pragma unroll
    for (int r = 0; r < MROWS; ++r) acc[r] = 0.f;
    for (int k = 0; k < K; ++k) {
        float bv = bp[(size_t)k * ldb];
#pragma unroll
        for (int r = 0; r < MROWS; ++r)
            acc[r] = fmaf(a[r * lda + k], bv, acc[r]);
    }
    float bb = bias ? bias[n] : 0.f;
#pragma unroll
    for (int r = 0; r < MROWS; ++r) {
        float v = acc[r] + bb;
        if (ACT == 3) v = gelu_f(v);
        C[(size_t)(m0 + r) * ldc + n] = v;
    }
}

// ---------------------------------------------------------------------------
// LayerNorm of the 4 last-token rows only.
// ---------------------------------------------------------------------------
__global__ __launch_bounds__(256) void ln_last_kernel(
    const float* __restrict__ h,
    const float* __restrict__ g, const float* __restrict__ be,
    float* __restrict__ out)
{
    __shared__ float sbuf[8];
    int b = blockIdx.x, tid = threadIdx.x;
    const float* row = h + (size_t)(b * kT + (kT - 1)) * kDMODEL;

    float v0 = row[tid], v1 = row[tid + 256];
    float s = v0 + v1;
    float q = v0 * v0 + v1 * v1;
#pragma unroll
    for (int m = 32; m >= 1; m >>= 1) {
        s += __shfl_xor(s, m, 64);
        q += __shfl_xor(q, m, 64);
    }
    int wid = tid >> 6;
    if ((tid & 63) == 0) { sbuf[wid] = s; sbuf[4 + wid] = q; }
    __syncthreads();
    if (tid == 0) {
        float S = 0.f, Q = 0.f;
        for (int i = 0; i < 4; ++i) { S += sbuf[i]; Q += sbuf[4 + i]; }
        sbuf[0] = S; sbuf[4] = Q;
    }
    __syncthreads();
    float mean = sbuf[0] * (1.f / kDMODEL);
    float var  = sbuf[4] * (1.f / kDMODEL) - mean * mean;
    float inv  = rsqrtf(var + 1e-5f);
    out[b * kDMODEL + tid]       = (v0 - mean) * inv * g[tid]       + be[tid];
    out[b * kDMODEL + tid + 256] = (v1 - mean) * inv * g[tid + 256] + be[tid + 256];
}

// ---------------------------------------------------------------------------
extern "C" void kernel_launch(void* const* d_in, const int* in_sizes, int n_in,
                              void* d_out, int out_size, void* d_ws, size_t ws_size,
                              hipStream_t stream)
{
    const float* x      = (const float*)d_in[0];
    const float* W_in   = (const float*)d_in[1];
    const float* b_in   = (const float*)d_in[2];
    const float* W_xz   = (const float*)d_in[3];   // (2,512,2048)
    const float* conv_w = (const float*)d_in[4];
    const float* conv_b = (const float*)d_in[5];
    const float* W_xp   = (const float*)d_in[6];   // (2,1024,160)
    const float* W_dt   = (const float*)d_in[7];   // (2,32,1024)
    const float* b_dt   = (const float*)d_in[8];
    const float* A_log  = (const float*)d_in[9];
    const float* D_skip = (const float*)d_in[10];
    const float* W_out  = (const float*)d_in[11];  // (2,1024,512)
    const float* ln_g   = (const float*)d_in[12];
    const float* ln_b   = (const float*)d_in[13];
    const float* W_h1   = (const float*)d_in[14];
    const float* b_h1   = (const float*)d_in[15];
    const float* W_h2   = (const float*)d_in[16];
    const float* b_h2   = (const float*)d_in[17];
    float* out = (float*)d_out;

    // Workspace layout
    char* p = (char*)d_ws;
    auto alloc = [&](size_t bytes) { char* q = p; p += (bytes + 255) & ~(size_t)255; return q; };
    float*          h       = (float*)         alloc((size_t)kBT * kDMODEL * 4);
    __hip_bfloat16* h_bf    = (__hip_bfloat16*)alloc((size_t)kBT * kDMODEL * 2);
    float*          xb      = (float*)         alloc((size_t)kBT * kDINNER * 4);  // reused as dt
    __hip_bfloat16* z_bf    = (__hip_bfloat16*)alloc((size_t)kBT * kDINNER * 2);
    __hip_bfloat16* xc_bf   = (__hip_bfloat16*)alloc((size_t)kBT * kDINNER * 2);
    float*          xdb     = (float*)         alloc((size_t)kBT * kXPAD * 4);
    __hip_bfloat16* xdb_bf  = (__hip_bfloat16*)alloc((size_t)kBT * kXPAD * 2);
    __hip_bfloat16* ys_bf   = (__hip_bfloat16*)alloc((size_t)kBT * kDINNER * 2);
    __hip_bfloat16* wxz_bt  = (__hip_bfloat16*)alloc((size_t)2 * 2048 * 512 * 2);
    __hip_bfloat16* wxp_bt  = (__hip_bfloat16*)alloc((size_t)2 * 256 * 1024 * 2);
    __hip_bfloat16* wdt_bt  = (__hip_bfloat16*)alloc((size_t)2 * 1024 * 64 * 2);
    __hip_bfloat16* wout_bt = (__hip_bfloat16*)alloc((size_t)2 * 512 * 1024 * 2);
    float*          lnb     = (float*)         alloc(kB * kDMODEL * 4);
    float*          hid     = (float*)         alloc(kB * kDMODEL * 4);
    float*          dtb     = xb;

    // Weight transposes for BOTH layers, hoisted (batched over blockIdx.z)
    wtrans_kernel<<<dim3(64, 16, 2), 256, 0, stream>>>(W_xz, 512,  2048, 512 * 2048, wxz_bt,  512,  2048 * 512);
    wtrans_kernel<<<dim3(8,  32, 2), 256, 0, stream>>>(W_xp, 1024, 160,  1024 * 160, wxp_bt,  1024, 256 * 1024);
    wtrans_kernel<<<dim3(32, 2,  2), 256, 0, stream>>>(W_dt, 32,   1024, 32 * 1024,  wdt_bt,  64,   1024 * 64);
    wtrans_kernel<<<dim3(16, 32, 2), 256, 0, stream>>>(W_out, 1024, 512, 1024 * 512, wout_bt, 1024, 512 * 1024);

    // Input projection
    in_proj_kernel<<<(kBT * kDMODEL) / 256, 256, 0, stream>>>(x, W_in, b_in, h, h_bf);

    for (int l = 0; l < kNLAYER; ++l) {
        const float* cw_l  = conv_w + (size_t)l * kDINNER * 4;
        const float* cb_l  = conv_b + (size_t)l * kDINNER;
        const float* bdt_l = b_dt   + (size_t)l * kDINNER;
        const float* Al_l  = A_log  + (size_t)l * kDINNER * kDSTATE;
        const float* Dsk_l = D_skip + (size_t)l * kDINNER;
        const __hip_bfloat16* wxz_l  = wxz_bt  + (size_t)l * 2048 * 512;
        const __hip_bfloat16* wxp_l  = wxp_bt  + (size_t)l * 256 * 1024;
        const __hip_bfloat16* wdt_l  = wdt_bt  + (size_t)l * 1024 * 64;
        const __hip_bfloat16* wout_l = wout_bt + (size_t)l * 512 * 1024;

        // xz = h @ W_xz : xb (f32) + z (silu, bf16)
        mfma_gemm_bt<0><<<dim3(16, 32), 256, 0, stream>>>(
            h_bf, kDMODEL, wxz_l, 512, nullptr, xb, kDINNER, z_bf, kDMODEL);
        // conv -> xc (bf16)
        conv_silu_kernel<<<(kBT * kDINNER) / 256, 256, 0, stream>>>(xb, cw_l, cb_l, xc_bf);
        // xdb = xc @ W_xproj  (f32 + bf16, ldc=256 padded)
        mfma_gemm_bt<1><<<dim3(2, 32), 256, 0, stream>>>(
            xc_bf, kDINNER, wxp_l, 1024, nullptr, xdb, kXPAD, xdb_bf, kDINNER);
        // dt = softplus(xdb[:, :32] @ W_dt + b_dt)   (K padded to 64)
        mfma_gemm_bt<2><<<dim3(8, 32), 256, 0, stream>>>(
            xdb_bf, kXPAD, wdt_l, 64, bdt_l, dtb, kDINNER, nullptr, 64);
        // scan + gate -> ys (bf16)
        scan_kernel<<<kB * kDINNER / 4, 256, 0, stream>>>(
            dtb, xdb, xc_bf, z_bf, Al_l, Dsk_l, ys_bf);
        // h = ys @ W_out  (f32 + bf16)
        mfma_gemm_bt<1><<<dim3(4, 32), 256, 0, stream>>>(
            ys_bf, kDINNER, wout_l, 1024, nullptr, h, kDMODEL, h_bf, kDINNER);
    }

    // Tail: LN on last tokens + 2-layer head (tiny, f32)
    ln_last_kernel<<<kB, 256, 0, stream>>>(h, ln_g, ln_b, lnb);
    gemm_kernel<4, 3><<<dim3(2, 1), 256, 0, stream>>>(
        lnb, kDMODEL, W_h1, kDMODEL, b_h1, hid, kDMODEL, kDMODEL, kDMODEL);
    gemm_kernel<4, 0><<<dim3(1, 1), 256, 0, stream>>>(
        hid, kDMODEL, W_h2, kHOR * kDOUT, b_h2, out, kHOR * kDOUT, kHOR * kDOUT, kDMODEL);
}

// Round 5
// 544.553 us; speedup vs baseline: 8.9888x; 1.5174x over previous
//
#include <hip/hip_runtime.h>
#include <hip/hip_bf16.h>

// Problem constants
static constexpr int kB      = 4;
static constexpr int kT      = 1024;
static constexpr int kDIN    = 8;
static constexpr int kDMODEL = 512;
static constexpr int kNLAYER = 2;
static constexpr int kHOR    = 24;
static constexpr int kDOUT   = 8;
static constexpr int kDSTATE = 64;
static constexpr int kDINNER = 1024;
static constexpr int kDTRANK = 32;
static constexpr int kXPROJ  = 160;          // 32 + 64 + 64
static constexpr int kXPAD   = 256;          // padded xdb row stride
static constexpr int kBT     = kB * kT;      // 4096

typedef __bf16 bf16x8 __attribute__((ext_vector_type(8)));
typedef float  f32x4  __attribute__((ext_vector_type(4)));

__device__ __forceinline__ float silu_f(float x)     { return x / (1.f + __expf(-x)); }
__device__ __forceinline__ float softplus_f(float x) { return (x > 20.f) ? x : log1pf(__expf(x)); }
__device__ __forceinline__ float gelu_f(float x)     { return 0.5f * x * (1.f + erff(x * 0.70710678118654752f)); }

// async global->LDS 16B
__device__ __forceinline__ void gld_lds16(const void* g, void* l) {
    __builtin_amdgcn_global_load_lds(
        (const __attribute__((address_space(1))) unsigned int*)g,
        (__attribute__((address_space(3))) unsigned int*)l, 16, 0, 0);
}

// ---------------------------------------------------------------------------
// Weight transpose + f32->bf16: out[n][k] = bf16(in[k][n]), zero-pad OOB.
// Batched over layers via blockIdx.z.
// ---------------------------------------------------------------------------
__global__ __launch_bounds__(256) void wtrans_kernel(
    const float* __restrict__ in, int K, int N, int in_lstride,
    __hip_bfloat16* __restrict__ out, int Kpad, int out_lstride)
{
    __shared__ float tile[32][33];
    const int tid = threadIdx.x;
    const int n0 = blockIdx.x * 32;
    const int k0 = blockIdx.y * 32;
    const float* inl = in + (size_t)blockIdx.z * in_lstride;
    __hip_bfloat16* outl = out + (size_t)blockIdx.z * out_lstride;

#pragma unroll
    for (int p = 0; p < 4; ++p) {
        int idx = p * 256 + tid;
        int ki = idx >> 5, ni = idx & 31;
        float v = 0.f;
        if (k0 + ki < K && n0 + ni < N) v = inl[(size_t)(k0 + ki) * N + n0 + ni];
        tile[ki][ni] = v;
    }
    __syncthreads();
#pragma unroll
    for (int p = 0; p < 4; ++p) {
        int idx = p * 256 + tid;
        int ni = idx >> 5, ki = idx & 31;
        outl[(size_t)(n0 + ni) * Kpad + k0 + ki] = __float2bfloat16(tile[ki][ni]);
    }
}

// ---------------------------------------------------------------------------
// MFMA bf16 GEMM, B-transposed. 128x128 tile, BK=64, 4 waves (2x2).
// Staging via global_load_lds width-16 (no VGPR round trip).
// MODE 0: XZ split (col<1024 -> f32 xb ; col>=1024 -> bf16 silu -> z)
// MODE 1: plain f32 C + bf16 C2
// MODE 2: softplus(v + bias[col]) -> f32 C
// ---------------------------------------------------------------------------
template<int MODE>
__global__ __launch_bounds__(256) void mfma_gemm_bt(
    const __hip_bfloat16* __restrict__ A, int lda,
    const __hip_bfloat16* __restrict__ BT, int ldb,
    const float* __restrict__ bias,
    float* __restrict__ C, int ldc,
    void* __restrict__ C2,
    int K)
{
    __shared__ __align__(16) __hip_bfloat16 sA[128][64];
    __shared__ __align__(16) __hip_bfloat16 sB[128][64];

    const int tid  = threadIdx.x;
    const int lane = tid & 63;
    const int w    = tid >> 6;
    const int wm   = w >> 1, wn = w & 1;
    const int m0   = blockIdx.y * 128;
    const int n0   = blockIdx.x * 128;

    f32x4 acc[4][4] = {};

    const int lrow = lane & 15;
    const int lk   = (lane >> 4) << 3;

    const int grow = tid >> 3;
    const int gcol = (tid & 7) * 8;
    char* ldsA = (char*)&sA[0][0] + w * 1024;
    char* ldsB = (char*)&sB[0][0] + w * 1024;

    for (int k0 = 0; k0 < K; k0 += 64) {
        __syncthreads();
#pragma unroll
        for (int p = 0; p < 4; ++p) {
            gld_lds16(A  + (size_t)(m0 + grow + p * 32) * lda + k0 + gcol, ldsA + p * 4096);
            gld_lds16(BT + (size_t)(n0 + grow + p * 32) * ldb + k0 + gcol, ldsB + p * 4096);
        }
        __syncthreads();
#pragma unroll
        for (int ks = 0; ks < 2; ++ks) {
            bf16x8 af[4], bfr[4];
#pragma unroll
            for (int i = 0; i < 4; ++i) {
                af[i]  = *reinterpret_cast<const bf16x8*>(&sA[wm * 64 + i * 16 + lrow][ks * 32 + lk]);
                bfr[i] = *reinterpret_cast<const bf16x8*>(&sB[wn * 64 + i * 16 + lrow][ks * 32 + lk]);
            }
#pragma unroll
            for (int i = 0; i < 4; ++i)
#pragma unroll
                for (int j = 0; j < 4; ++j)
                    acc[i][j] = __builtin_amdgcn_mfma_f32_16x16x32_bf16(af[i], bfr[j], acc[i][j], 0, 0, 0);
        }
    }

    const int crow = (lane >> 4) * 4;
    const int ccol = lane & 15;
#pragma unroll
    for (int i = 0; i < 4; ++i) {
#pragma unroll
        for (int j = 0; j < 4; ++j) {
#pragma unroll
            for (int r = 0; r < 4; ++r) {
                int row = m0 + wm * 64 + i * 16 + crow + r;
                int col = n0 + wn * 64 + j * 16 + ccol;
                float v = acc[i][j][r];
                if (MODE == 0) {
                    if (col < kDINNER)
                        C[(size_t)row * ldc + col] = v;
                    else
                        ((__hip_bfloat16*)C2)[(size_t)row * ldc + (col - kDINNER)] =
                            __float2bfloat16(silu_f(v));
                } else if (MODE == 1) {
                    C[(size_t)row * ldc + col] = v;
                    ((__hip_bfloat16*)C2)[(size_t)row * ldc + col] = __float2bfloat16(v);
                } else {
                    C[(size_t)row * ldc + col] = softplus_f(v + bias[col]);
                }
            }
        }
    }
}

// ---------------------------------------------------------------------------
// Input projection: h = x @ W_in + b_in  (K=8), writes f32 + bf16.
// ---------------------------------------------------------------------------
__global__ __launch_bounds__(256) void in_proj_kernel(
    const float* __restrict__ x, const float* __restrict__ W,
    const float* __restrict__ b,
    float* __restrict__ h, __hip_bfloat16* __restrict__ hb)
{
    int idx = blockIdx.x * 256 + threadIdx.x;
    int m = idx >> 9, n = idx & 511;
    float acc = b[n];
    const float* xr = x + m * kDIN;
#pragma unroll
    for (int k = 0; k < kDIN; ++k)
        acc = fmaf(xr[k], W[k * kDMODEL + n], acc);
    h[idx]  = acc;
    hb[idx] = __float2bfloat16(acc);
}

// ---------------------------------------------------------------------------
// Depthwise causal conv (width 4) + bias + SiLU -> bf16.
// ---------------------------------------------------------------------------
__global__ __launch_bounds__(256) void conv_silu_kernel(
    const float* __restrict__ xb,
    const float* __restrict__ cw, const float* __restrict__ cb,
    __hip_bfloat16* __restrict__ xc)
{
    int idx = blockIdx.x * 256 + threadIdx.x;
    int d   = idx & (kDINNER - 1);
    int bt  = idx >> 10;
    int t   = bt & (kT - 1);

    float4 wv = *reinterpret_cast<const float4*>(cw + d * 4);
    float acc = cb[d];
    const float* base = xb + (size_t)bt * kDINNER + d;
    if (t >= 3) {
        acc = fmaf(base[-3 * kDINNER], wv.x, acc);
        acc = fmaf(base[-2 * kDINNER], wv.y, acc);
        acc = fmaf(base[-1 * kDINNER], wv.z, acc);
        acc = fmaf(base[0],            wv.w, acc);
    } else {
        if (t >= 2) acc = fmaf(base[-2 * kDINNER], wv.y, acc);
        if (t >= 1) acc = fmaf(base[-1 * kDINNER], wv.z, acc);
        acc = fmaf(base[0], wv.w, acc);
    }
    xc[idx] = __float2bfloat16(silu_f(acc));
}

// ---------------------------------------------------------------------------
// Selective scan. Block = 4 waves (channels d0..d0+3, same b); lane = state n.
// 32-step chunks in LDS. Per-step work is recurrence only; the C-dot
// cross-lane reduce is BATCHED: per-lane partials yv[0..31] in registers,
// then a select+shfl_xor halving tree (31 combines + 1 xor-32) produces,
// in lane L, the full 64-lane sum for step (L&31).  ~4 inst/step vs 12.
// ---------------------------------------------------------------------------
__global__ __launch_bounds__(256) void scan_kernel(
    const float* __restrict__ dt,            // (bt,1024) f32
    const float* __restrict__ xdb,           // (bt,256)  f32: [32:96)=B [96:160)=C
    const __hip_bfloat16* __restrict__ xc,   // (bt,1024)
    const __hip_bfloat16* __restrict__ zs,   // (bt,1024) silu(z)
    const float* __restrict__ Alog,          // (1024,64)
    const float* __restrict__ Dsk,           // (1024,)
    __hip_bfloat16* __restrict__ yg)         // (bt,1024)
{
    __shared__ float sBC[32][128];
    __shared__ float sDX[32][4][2];   // [t][w][0]=dt, [1]=xc
    __shared__ float sY [32][4];

    const int tid  = threadIdx.x;
    const int lane = tid & 63;
    const int w    = tid >> 6;
    const int bb   = blockIdx.x;
    const int b    = bb >> 8;
    const int d0   = (bb & 255) * 4;
    const int d    = d0 + w;

    const float a   = -__expf(Alog[d * kDSTATE + lane]);
    const float dsk = Dsk[d];
    float s = 0.f;
    const size_t rowbase = (size_t)b * kT;

    const int hr = (tid & 127) >> 2, hj = tid & 3, hs = tid >> 7;

    for (int c = 0; c < kT / 32; ++c) {
        const int t0 = c * 32;
        __syncthreads();
        // stage B/C: 32 rows x 128 f32
#pragma unroll
        for (int p = 0; p < 4; ++p) {
            int idx = tid + p * 256;
            int r = idx >> 5, c4 = idx & 31;
            *reinterpret_cast<float4*>(&sBC[r][c4 * 4]) =
                *reinterpret_cast<const float4*>(xdb + (rowbase + t0 + r) * kXPAD + kDTRANK + c4 * 4);
        }
        {
            size_t g = (rowbase + t0 + hr) * kDINNER + d0 + hj;
            if (hs == 0) sDX[hr][hj][0] = dt[g];
            else         sDX[hr][hj][1] = __bfloat162float(xc[g]);
        }
        __syncthreads();

        // recurrence: per-lane y partials for all 32 steps (registers)
        float yv[32];
#pragma unroll
        for (int i = 0; i < 32; ++i) {
            float Bv  = sBC[i][lane];
            float Cv  = sBC[i][64 + lane];
            float dtv = sDX[i][w][0];
            float xv  = sDX[i][w][1];
            float dA  = __expf(dtv * a);
            s = fmaf(dA, s, (dtv * xv) * Bv);
            yv[i] = s * Cv;
        }

        // batched transpose-reduce: lane L -> full sum of step (L&31)
#pragma unroll
        for (int j = 0; j < 5; ++j) {
            const int S = 1 << j;
            const bool sel = (lane & S) != 0;
#pragma unroll
            for (int m = 0; m < (32 >> (j + 1)); ++m) {
                float av = yv[2 * m], bv2 = yv[2 * m + 1];
                float cv = sel ? bv2 : av;
                float dv = sel ? av : bv2;
                yv[m] = cv + __shfl_xor(dv, S, 64);
            }
        }
        float y = yv[0];
        y += __shfl_xor(y, 32, 64);

        if (lane < 32) sY[lane][w] = fmaf(dsk, sDX[lane][w][1], y);
        __syncthreads();
        if (tid < 128) {
            int r = tid >> 2, j = tid & 3;
            size_t g = (rowbase + t0 + r) * kDINNER + d0 + j;
            yg[g] = __float2bfloat16(sY[r][j] * __bfloat162float(zs[g]));
        }
    }
}

// ---------------------------------------------------------------------------
// Head GEMM: C[b][n] = act(sum_k A[b][k]*B[k][n] + bias[n]), b=0..3.
// Compile-time K -> unrolled, 16 loads in flight (the runtime-K version
// serialized at ~1 load/iteration: 200us for a 2-MFLOP GEMM).
// 64 columns/block x 4 batch-waves.
// ---------------------------------------------------------------------------
template<int N, int KK, int ACT>
__global__ __launch_bounds__(256) void head_gemm(
    const float* __restrict__ A,
    const float* __restrict__ B,
    const float* __restrict__ bias,
    float* __restrict__ C)
{
    const int n = blockIdx.x * 64 + (threadIdx.x & 63);
    const int b = threadIdx.x >> 6;
    const float* a  = A + b * KK;
    const float* bp = B + n;
    float acc = 0.f;
#pragma unroll 16
    for (int k = 0; k < KK; ++k)
        acc = fmaf(a[k], bp[(size_t)k * N], acc);
    float v = acc + bias[n];
    if (ACT == 3) v = gelu_f(v);
    C[(size_t)b * N + n] = v;
}

// ---------------------------------------------------------------------------
// LayerNorm of the 4 last-token rows only.
// ---------------------------------------------------------------------------
__global__ __launch_bounds__(256) void ln_last_kernel(
    const float* __restrict__ h,
    const float* __restrict__ g, const float* __restrict__ be,
    float* __restrict__ out)
{
    __shared__ float sbuf[8];
    int b = blockIdx.x, tid = threadIdx.x;
    const float* row = h + (size_t)(b * kT + (kT - 1)) * kDMODEL;

    float v0 = row[tid], v1 = row[tid + 256];
    float s = v0 + v1;
    float q = v0 * v0 + v1 * v1;
#pragma unroll
    for (int m = 32; m >= 1; m >>= 1) {
        s += __shfl_xor(s, m, 64);
        q += __shfl_xor(q, m, 64);
    }
    int wid = tid >> 6;
    if ((tid & 63) == 0) { sbuf[wid] = s; sbuf[4 + wid] = q; }
    __syncthreads();
    if (tid == 0) {
        float S = 0.f, Q = 0.f;
        for (int i = 0; i < 4; ++i) { S += sbuf[i]; Q += sbuf[4 + i]; }
        sbuf[0] = S; sbuf[4] = Q;
    }
    __syncthreads();
    float mean = sbuf[0] * (1.f / kDMODEL);
    float var  = sbuf[4] * (1.f / kDMODEL) - mean * mean;
    float inv  = rsqrtf(var + 1e-5f);
    out[b * kDMODEL + tid]       = (v0 - mean) * inv * g[tid]       + be[tid];
    out[b * kDMODEL + tid + 256] = (v1 - mean) * inv * g[tid + 256] + be[tid + 256];
}

// ---------------------------------------------------------------------------
extern "C" void kernel_launch(void* const* d_in, const int* in_sizes, int n_in,
                              void* d_out, int out_size, void* d_ws, size_t ws_size,
                              hipStream_t stream)
{
    const float* x      = (const float*)d_in[0];
    const float* W_in   = (const float*)d_in[1];
    const float* b_in   = (const float*)d_in[2];
    const float* W_xz   = (const float*)d_in[3];   // (2,512,2048)
    const float* conv_w = (const float*)d_in[4];
    const float* conv_b = (const float*)d_in[5];
    const float* W_xp   = (const float*)d_in[6];   // (2,1024,160)
    const float* W_dt   = (const float*)d_in[7];   // (2,32,1024)
    const float* b_dt   = (const float*)d_in[8];
    const float* A_log  = (const float*)d_in[9];
    const float* D_skip = (const float*)d_in[10];
    const float* W_out  = (const float*)d_in[11];  // (2,1024,512)
    const float* ln_g   = (const float*)d_in[12];
    const float* ln_b   = (const float*)d_in[13];
    const float* W_h1   = (const float*)d_in[14];
    const float* b_h1   = (const float*)d_in[15];
    const float* W_h2   = (const float*)d_in[16];
    const float* b_h2   = (const float*)d_in[17];
    float* out = (float*)d_out;

    // Workspace layout
    char* p = (char*)d_ws;
    auto alloc = [&](size_t bytes) { char* q = p; p += (bytes + 255) & ~(size_t)255; return q; };
    float*          h       = (float*)         alloc((size_t)kBT * kDMODEL * 4);
    __hip_bfloat16* h_bf    = (__hip_bfloat16*)alloc((size_t)kBT * kDMODEL * 2);
    float*          xb      = (float*)         alloc((size_t)kBT * kDINNER * 4);  // reused as dt
    __hip_bfloat16* z_bf    = (__hip_bfloat16*)alloc((size_t)kBT * kDINNER * 2);
    __hip_bfloat16* xc_bf   = (__hip_bfloat16*)alloc((size_t)kBT * kDINNER * 2);
    float*          xdb     = (float*)         alloc((size_t)kBT * kXPAD * 4);
    __hip_bfloat16* xdb_bf  = (__hip_bfloat16*)alloc((size_t)kBT * kXPAD * 2);
    __hip_bfloat16* ys_bf   = (__hip_bfloat16*)alloc((size_t)kBT * kDINNER * 2);
    __hip_bfloat16* wxz_bt  = (__hip_bfloat16*)alloc((size_t)2 * 2048 * 512 * 2);
    __hip_bfloat16* wxp_bt  = (__hip_bfloat16*)alloc((size_t)2 * 256 * 1024 * 2);
    __hip_bfloat16* wdt_bt  = (__hip_bfloat16*)alloc((size_t)2 * 1024 * 64 * 2);
    __hip_bfloat16* wout_bt = (__hip_bfloat16*)alloc((size_t)2 * 512 * 1024 * 2);
    float*          lnb     = (float*)         alloc(kB * kDMODEL * 4);
    float*          hid     = (float*)         alloc(kB * kDMODEL * 4);
    float*          dtb     = xb;

    // Weight transposes for BOTH layers, hoisted (batched over blockIdx.z)
    wtrans_kernel<<<dim3(64, 16, 2), 256, 0, stream>>>(W_xz, 512,  2048, 512 * 2048, wxz_bt,  512,  2048 * 512);
    wtrans_kernel<<<dim3(8,  32, 2), 256, 0, stream>>>(W_xp, 1024, 160,  1024 * 160, wxp_bt,  1024, 256 * 1024);
    wtrans_kernel<<<dim3(32, 2,  2), 256, 0, stream>>>(W_dt, 32,   1024, 32 * 1024,  wdt_bt,  64,   1024 * 64);
    wtrans_kernel<<<dim3(16, 32, 2), 256, 0, stream>>>(W_out, 1024, 512, 1024 * 512, wout_bt, 1024, 512 * 1024);

    // Input projection
    in_proj_kernel<<<(kBT * kDMODEL) / 256, 256, 0, stream>>>(x, W_in, b_in, h, h_bf);

    for (int l = 0; l < kNLAYER; ++l) {
        const float* cw_l  = conv_w + (size_t)l * kDINNER * 4;
        const float* cb_l  = conv_b + (size_t)l * kDINNER;
        const float* bdt_l = b_dt   + (size_t)l * kDINNER;
        const float* Al_l  = A_log  + (size_t)l * kDINNER * kDSTATE;
        const float* Dsk_l = D_skip + (size_t)l * kDINNER;
        const __hip_bfloat16* wxz_l  = wxz_bt  + (size_t)l * 2048 * 512;
        const __hip_bfloat16* wxp_l  = wxp_bt  + (size_t)l * 256 * 1024;
        const __hip_bfloat16* wdt_l  = wdt_bt  + (size_t)l * 1024 * 64;
        const __hip_bfloat16* wout_l = wout_bt + (size_t)l * 512 * 1024;

        // xz = h @ W_xz : xb (f32) + z (silu, bf16)
        mfma_gemm_bt<0><<<dim3(16, 32), 256, 0, stream>>>(
            h_bf, kDMODEL, wxz_l, 512, nullptr, xb, kDINNER, z_bf, kDMODEL);
        // conv -> xc (bf16)
        conv_silu_kernel<<<(kBT * kDINNER) / 256, 256, 0, stream>>>(xb, cw_l, cb_l, xc_bf);
        // xdb = xc @ W_xproj  (f32 + bf16, ldc=256 padded)
        mfma_gemm_bt<1><<<dim3(2, 32), 256, 0, stream>>>(
            xc_bf, kDINNER, wxp_l, 1024, nullptr, xdb, kXPAD, xdb_bf, kDINNER);
        // dt = softplus(xdb[:, :32] @ W_dt + b_dt)   (K padded to 64)
        mfma_gemm_bt<2><<<dim3(8, 32), 256, 0, stream>>>(
            xdb_bf, kXPAD, wdt_l, 64, bdt_l, dtb, kDINNER, nullptr, 64);
        // scan + gate -> ys (bf16)
        scan_kernel<<<kB * kDINNER / 4, 256, 0, stream>>>(
            dtb, xdb, xc_bf, z_bf, Al_l, Dsk_l, ys_bf);
        // h = ys @ W_out  (f32 + bf16)
        mfma_gemm_bt<1><<<dim3(4, 32), 256, 0, stream>>>(
            ys_bf, kDINNER, wout_l, 1024, nullptr, h, kDMODEL, h_bf, kDINNER);
    }

    // Tail: LN on last tokens + 2-layer head (K-unrolled f32)
    ln_last_kernel<<<kB, 256, 0, stream>>>(h, ln_g, ln_b, lnb);
    head_gemm<kDMODEL, kDMODEL, 3><<<kDMODEL / 64, 256, 0, stream>>>(lnb, W_h1, b_h1, hid);
    head_gemm<kHOR * kDOUT, kDMODEL, 0><<<(kHOR * kDOUT) / 64, 256, 0, stream>>>(hid, W_h2, b_h2, out);
}

// Round 6
// 528.482 us; speedup vs baseline: 9.2621x; 1.0304x over previous
//
#include <hip/hip_runtime.h>
#include <hip/hip_bf16.h>

// Problem constants
static constexpr int kB      = 4;
static constexpr int kT      = 1024;
static constexpr int kDIN    = 8;
static constexpr int kDMODEL = 512;
static constexpr int kNLAYER = 2;
static constexpr int kHOR    = 24;
static constexpr int kDOUT   = 8;
static constexpr int kDSTATE = 64;
static constexpr int kDINNER = 1024;
static constexpr int kDTRANK = 32;
static constexpr int kXPROJ  = 160;          // 32 + 64 + 64
static constexpr int kXPAD   = 256;          // padded xdb row stride
static constexpr int kBT     = kB * kT;      // 4096

typedef __bf16 bf16x8 __attribute__((ext_vector_type(8)));
typedef float  f32x4  __attribute__((ext_vector_type(4)));

__device__ __forceinline__ float silu_f(float x)     { return x / (1.f + __expf(-x)); }
__device__ __forceinline__ float softplus_f(float x) { return (x > 20.f) ? x : log1pf(__expf(x)); }
__device__ __forceinline__ float gelu_f(float x)     { return 0.5f * x * (1.f + erff(x * 0.70710678118654752f)); }

// async global->LDS 16B
__device__ __forceinline__ void gld_lds16(const void* g, void* l) {
    __builtin_amdgcn_global_load_lds(
        (const __attribute__((address_space(1))) unsigned int*)g,
        (__attribute__((address_space(3))) unsigned int*)l, 16, 0, 0);
}

__device__ __forceinline__ float readlane_f(float v, int l) {
    return __int_as_float(__builtin_amdgcn_readlane(__float_as_int(v), l));
}
template<int CTRL>
__device__ __forceinline__ float dpp_mov(float v) {
    return __int_as_float(__builtin_amdgcn_update_dpp(
        0, __float_as_int(v), CTRL, 0xf, 0xf, false));
}

// ---------------------------------------------------------------------------
// Weight transpose + f32->bf16: out[n][k] = bf16(in[k][n]), zero-pad OOB.
// Batched over layers via blockIdx.z.
// ---------------------------------------------------------------------------
__global__ __launch_bounds__(256) void wtrans_kernel(
    const float* __restrict__ in, int K, int N, int in_lstride,
    __hip_bfloat16* __restrict__ out, int Kpad, int out_lstride)
{
    __shared__ float tile[32][33];
    const int tid = threadIdx.x;
    const int n0 = blockIdx.x * 32;
    const int k0 = blockIdx.y * 32;
    const float* inl = in + (size_t)blockIdx.z * in_lstride;
    __hip_bfloat16* outl = out + (size_t)blockIdx.z * out_lstride;

#pragma unroll
    for (int p = 0; p < 4; ++p) {
        int idx = p * 256 + tid;
        int ki = idx >> 5, ni = idx & 31;
        float v = 0.f;
        if (k0 + ki < K && n0 + ni < N) v = inl[(size_t)(k0 + ki) * N + n0 + ni];
        tile[ki][ni] = v;
    }
    __syncthreads();
#pragma unroll
    for (int p = 0; p < 4; ++p) {
        int idx = p * 256 + tid;
        int ni = idx >> 5, ki = idx & 31;
        outl[(size_t)(n0 + ni) * Kpad + k0 + ki] = __float2bfloat16(tile[ki][ni]);
    }
}

// ---------------------------------------------------------------------------
// MFMA bf16 GEMM, B-transposed. 128x128 tile, BK=64, 4 waves (2x2).
// Staging via global_load_lds width-16.
// MODE 1: plain f32 C + bf16 C2
// MODE 2: softplus(v + bias[col]) -> f32 C
// MODE 4: XZ split, both bf16 (col<1024 -> bf16 xb ; col>=1024 -> silu -> z)
// ---------------------------------------------------------------------------
template<int MODE>
__global__ __launch_bounds__(256) void mfma_gemm_bt(
    const __hip_bfloat16* __restrict__ A, int lda,
    const __hip_bfloat16* __restrict__ BT, int ldb,
    const float* __restrict__ bias,
    float* __restrict__ C, int ldc,
    void* __restrict__ C2,
    int K)
{
    __shared__ __align__(16) __hip_bfloat16 sA[128][64];
    __shared__ __align__(16) __hip_bfloat16 sB[128][64];

    const int tid  = threadIdx.x;
    const int lane = tid & 63;
    const int w    = tid >> 6;
    const int wm   = w >> 1, wn = w & 1;
    const int m0   = blockIdx.y * 128;
    const int n0   = blockIdx.x * 128;

    f32x4 acc[4][4] = {};

    const int lrow = lane & 15;
    const int lk   = (lane >> 4) << 3;

    const int grow = tid >> 3;
    const int gcol = (tid & 7) * 8;
    char* ldsA = (char*)&sA[0][0] + w * 1024;
    char* ldsB = (char*)&sB[0][0] + w * 1024;

    for (int k0 = 0; k0 < K; k0 += 64) {
        __syncthreads();
#pragma unroll
        for (int p = 0; p < 4; ++p) {
            gld_lds16(A  + (size_t)(m0 + grow + p * 32) * lda + k0 + gcol, ldsA + p * 4096);
            gld_lds16(BT + (size_t)(n0 + grow + p * 32) * ldb + k0 + gcol, ldsB + p * 4096);
        }
        __syncthreads();
#pragma unroll
        for (int ks = 0; ks < 2; ++ks) {
            bf16x8 af[4], bfr[4];
#pragma unroll
            for (int i = 0; i < 4; ++i) {
                af[i]  = *reinterpret_cast<const bf16x8*>(&sA[wm * 64 + i * 16 + lrow][ks * 32 + lk]);
                bfr[i] = *reinterpret_cast<const bf16x8*>(&sB[wn * 64 + i * 16 + lrow][ks * 32 + lk]);
            }
#pragma unroll
            for (int i = 0; i < 4; ++i)
#pragma unroll
                for (int j = 0; j < 4; ++j)
                    acc[i][j] = __builtin_amdgcn_mfma_f32_16x16x32_bf16(af[i], bfr[j], acc[i][j], 0, 0, 0);
        }
    }

    const int crow = (lane >> 4) * 4;
    const int ccol = lane & 15;
#pragma unroll
    for (int i = 0; i < 4; ++i) {
#pragma unroll
        for (int j = 0; j < 4; ++j) {
#pragma unroll
            for (int r = 0; r < 4; ++r) {
                int row = m0 + wm * 64 + i * 16 + crow + r;
                int col = n0 + wn * 64 + j * 16 + ccol;
                float v = acc[i][j][r];
                if (MODE == 1) {
                    C[(size_t)row * ldc + col] = v;
                    ((__hip_bfloat16*)C2)[(size_t)row * ldc + col] = __float2bfloat16(v);
                } else if (MODE == 2) {
                    C[(size_t)row * ldc + col] = softplus_f(v + bias[col]);
                } else {  // MODE 4
                    if (col < kDINNER)
                        ((__hip_bfloat16*)C)[(size_t)row * ldc + col] = __float2bfloat16(v);
                    else
                        ((__hip_bfloat16*)C2)[(size_t)row * ldc + (col - kDINNER)] =
                            __float2bfloat16(silu_f(v));
                }
            }
        }
    }
}

// ---------------------------------------------------------------------------
// Input projection: h = x @ W_in + b_in  (K=8), writes f32 + bf16.
// ---------------------------------------------------------------------------
__global__ __launch_bounds__(256) void in_proj_kernel(
    const float* __restrict__ x, const float* __restrict__ W,
    const float* __restrict__ b,
    float* __restrict__ h, __hip_bfloat16* __restrict__ hb)
{
    int idx = blockIdx.x * 256 + threadIdx.x;
    int m = idx >> 9, n = idx & 511;
    float acc = b[n];
    const float* xr = x + m * kDIN;
#pragma unroll
    for (int k = 0; k < kDIN; ++k)
        acc = fmaf(xr[k], W[k * kDMODEL + n], acc);
    h[idx]  = acc;
    hb[idx] = __float2bfloat16(acc);
}

// ---------------------------------------------------------------------------
// Depthwise causal conv (width 4) + bias + SiLU. bf16 in -> bf16 out.
// ---------------------------------------------------------------------------
__global__ __launch_bounds__(256) void conv_silu_kernel(
    const __hip_bfloat16* __restrict__ xb,
    const float* __restrict__ cw, const float* __restrict__ cb,
    __hip_bfloat16* __restrict__ xc)
{
    int idx = blockIdx.x * 256 + threadIdx.x;
    int d   = idx & (kDINNER - 1);
    int bt  = idx >> 10;
    int t   = bt & (kT - 1);

    float4 wv = *reinterpret_cast<const float4*>(cw + d * 4);
    float acc = cb[d];
    const __hip_bfloat16* base = xb + (size_t)bt * kDINNER + d;
    if (t >= 3) {
        acc = fmaf(__bfloat162float(base[-3 * kDINNER]), wv.x, acc);
        acc = fmaf(__bfloat162float(base[-2 * kDINNER]), wv.y, acc);
        acc = fmaf(__bfloat162float(base[-1 * kDINNER]), wv.z, acc);
        acc = fmaf(__bfloat162float(base[0]),            wv.w, acc);
    } else {
        if (t >= 2) acc = fmaf(__bfloat162float(base[-2 * kDINNER]), wv.y, acc);
        if (t >= 1) acc = fmaf(__bfloat162float(base[-1 * kDINNER]), wv.z, acc);
        acc = fmaf(__bfloat162float(base[0]), wv.w, acc);
    }
    xc[idx] = __float2bfloat16(silu_f(acc));
}

// ---------------------------------------------------------------------------
// Selective scan. Block = 4 waves (channels d0..d0+3, same b); lane = state n.
// XCD-aware remap: batch b owns XCD pair {2b,2b+1} -> its 512KB B/C panel
// stays L2-resident. 32-step chunks, double-buffered B/C via global_load_lds.
// dt/xc live in registers (lane = step of a 64-step pair), broadcast per step
// with v_readlane. Select+shuffle tree (DPP for S=1,2) reduces the C-dot.
// ---------------------------------------------------------------------------
__global__ __launch_bounds__(256, 4) void scan_kernel(
    const float* __restrict__ dt,            // (bt,1024) f32
    const float* __restrict__ xdb,           // (bt,256)  f32: [32:96)=B [96:160)=C
    const __hip_bfloat16* __restrict__ xc,   // (bt,1024)
    const __hip_bfloat16* __restrict__ zs,   // (bt,1024) silu(z)
    const float* __restrict__ Alog,          // (1024,64)
    const float* __restrict__ Dsk,           // (1024,)
    __hip_bfloat16* __restrict__ yg)         // (bt,1024)
{
    __shared__ __align__(16) float sBC[2][32][128];
    __shared__ float sY[2][32][4];

    const int tid  = threadIdx.x;
    const int lane = tid & 63;
    const int w    = tid >> 6;
    // XCD remap: consecutive blockIdx round-robin XCDs; cluster same-b on an
    // XCD pair so B/C is fetched to that L2 once.
    const int bb = blockIdx.x;
    const int b  = (bb & 7) >> 1;
    const int d0 = ((bb >> 3) + (bb & 1) * 128) * 4;
    const int d  = d0 + w;

    const float a2  = -__expf(Alog[d * kDSTATE + lane]) * 1.44269504f;  // log2e folded
    const float dsk = Dsk[d];
    const size_t rowbase = (size_t)b * kT;
    float s = 0.f;

    // stage chunk c (32 rows x 128 f32 of B|C) into sBC[buf]: 4 gld/wave
    auto stage = [&](int c, int buf) {
        const float* src = xdb + (rowbase + c * 32 + w * 8 + (lane >> 5)) * kXPAD
                               + kDTRANK + (lane & 31) * 4;
#pragma unroll
        for (int p = 0; p < 4; ++p)
            gld_lds16(src + p * 2 * kXPAD, &sBC[buf][w * 8 + p * 2][0]);
    };
    // load 64 steps (pair pr) of dt/xc for channel d; lane = step
    auto loadpair = [&](int pr, float& odt, float& oxc, float& odtx) {
        size_t row = rowbase + pr * 64 + lane;
        odt  = dt[row * kDINNER + d];
        oxc  = __bfloat162float(xc[row * kDINNER + d]);
        odtx = odt * oxc;
    };

    float vdt, vxc, vdtx;
    stage(0, 0);
    loadpair(0, vdt, vxc, vdtx);
    __syncthreads();

    for (int pr = 0; pr < kT / 64; ++pr) {
#pragma unroll
        for (int half = 0; half < 2; ++half) {
            const int c   = pr * 2 + half;
            const int buf = half;
            if (c + 1 < kT / 32) stage(c + 1, buf ^ 1);
            float ndt, nxc, ndtx;
            const bool ld = (half == 1) && (pr + 1 < kT / 64);
            if (ld) loadpair(pr + 1, ndt, nxc, ndtx);

            // recurrence: 32 steps, per-lane y partials in registers
            float yv[32];
#pragma unroll
            for (int i = 0; i < 32; ++i) {
                float Bv   = sBC[buf][i][lane];
                float Cv   = sBC[buf][i][64 + lane];
                float sdt  = readlane_f(vdt,  half * 32 + i);
                float sdtx = readlane_f(vdtx, half * 32 + i);
                float dA   = exp2f(sdt * a2);
                s = fmaf(dA, s, sdtx * Bv);
                yv[i] = s * Cv;
            }

            // transpose-reduce: lane L ends with step (L&31)'s 64-lane sum
            // level S=1 via DPP quad_perm [1,0,3,2]
#pragma unroll
            for (int m = 0; m < 16; ++m) {
                float av = yv[2 * m], bv = yv[2 * m + 1];
                float cv = (lane & 1) ? bv : av;
                float dv = (lane & 1) ? av : bv;
                yv[m] = cv + dpp_mov<0xB1>(dv);
            }
            // level S=2 via DPP quad_perm [2,3,0,1]
#pragma unroll
            for (int m = 0; m < 8; ++m) {
                float av = yv[2 * m], bv = yv[2 * m + 1];
                float cv = (lane & 2) ? bv : av;
                float dv = (lane & 2) ? av : bv;
                yv[m] = cv + dpp_mov<0x4E>(dv);
            }
            // levels S=4,8,16 via shfl_xor
#pragma unroll
            for (int j = 2; j < 5; ++j) {
                const int S = 1 << j;
#pragma unroll
                for (int m = 0; m < (32 >> (j + 1)); ++m) {
                    float av = yv[2 * m], bv = yv[2 * m + 1];
                    float cv = (lane & S) ? bv : av;
                    float dv = (lane & S) ? av : bv;
                    yv[m] = cv + __shfl_xor(dv, S, 64);
                }
            }
            float y = yv[0];
            y += __shfl_xor(y, 32, 64);

            // lanes of the active half hold vxc for their step
            if ((lane & 32) == half * 32)
                sY[buf][lane & 31][w] = fmaf(dsk, vxc, y);
            __syncthreads();   // sY visible + staged gld for chunk c+1 drained

            if (tid < 128) {
                int r = tid >> 2, j2 = tid & 3;
                size_t g = (rowbase + c * 32 + r) * kDINNER + d0 + j2;
                yg[g] = __float2bfloat16(sY[buf][r][j2] * __bfloat162float(zs[g]));
            }
            if (ld) { vdt = ndt; vxc = nxc; vdtx = ndtx; }
        }
    }
}

// ---------------------------------------------------------------------------
// Head GEMM: C[b][n] = act(sum_k A[b][k]*B[k][n] + bias[n]), b=0..3.
// ---------------------------------------------------------------------------
template<int N, int KK, int ACT>
__global__ __launch_bounds__(256) void head_gemm(
    const float* __restrict__ A,
    const float* __restrict__ B,
    const float* __restrict__ bias,
    float* __restrict__ C)
{
    const int n = blockIdx.x * 64 + (threadIdx.x & 63);
    const int b = threadIdx.x >> 6;
    const float* a  = A + b * KK;
    const float* bp = B + n;
    float acc = 0.f;
#pragma unroll 16
    for (int k = 0; k < KK; ++k)
        acc = fmaf(a[k], bp[(size_t)k * N], acc);
    float v = acc + bias[n];
    if (ACT == 3) v = gelu_f(v);
    C[(size_t)b * N + n] = v;
}

// ---------------------------------------------------------------------------
// LayerNorm of the 4 last-token rows only.
// ---------------------------------------------------------------------------
__global__ __launch_bounds__(256) void ln_last_kernel(
    const float* __restrict__ h,
    const float* __restrict__ g, const float* __restrict__ be,
    float* __restrict__ out)
{
    __shared__ float sbuf[8];
    int b = blockIdx.x, tid = threadIdx.x;
    const float* row = h + (size_t)(b * kT + (kT - 1)) * kDMODEL;

    float v0 = row[tid], v1 = row[tid + 256];
    float s = v0 + v1;
    float q = v0 * v0 + v1 * v1;
#pragma unroll
    for (int m = 32; m >= 1; m >>= 1) {
        s += __shfl_xor(s, m, 64);
        q += __shfl_xor(q, m, 64);
    }
    int wid = tid >> 6;
    if ((tid & 63) == 0) { sbuf[wid] = s; sbuf[4 + wid] = q; }
    __syncthreads();
    if (tid == 0) {
        float S = 0.f, Q = 0.f;
        for (int i = 0; i < 4; ++i) { S += sbuf[i]; Q += sbuf[4 + i]; }
        sbuf[0] = S; sbuf[4] = Q;
    }
    __syncthreads();
    float mean = sbuf[0] * (1.f / kDMODEL);
    float var  = sbuf[4] * (1.f / kDMODEL) - mean * mean;
    float inv  = rsqrtf(var + 1e-5f);
    out[b * kDMODEL + tid]       = (v0 - mean) * inv * g[tid]       + be[tid];
    out[b * kDMODEL + tid + 256] = (v1 - mean) * inv * g[tid + 256] + be[tid + 256];
}

// ---------------------------------------------------------------------------
extern "C" void kernel_launch(void* const* d_in, const int* in_sizes, int n_in,
                              void* d_out, int out_size, void* d_ws, size_t ws_size,
                              hipStream_t stream)
{
    const float* x      = (const float*)d_in[0];
    const float* W_in   = (const float*)d_in[1];
    const float* b_in   = (const float*)d_in[2];
    const float* W_xz   = (const float*)d_in[3];   // (2,512,2048)
    const float* conv_w = (const float*)d_in[4];
    const float* conv_b = (const float*)d_in[5];
    const float* W_xp   = (const float*)d_in[6];   // (2,1024,160)
    const float* W_dt   = (const float*)d_in[7];   // (2,32,1024)
    const float* b_dt   = (const float*)d_in[8];
    const float* A_log  = (const float*)d_in[9];
    const float* D_skip = (const float*)d_in[10];
    const float* W_out  = (const float*)d_in[11];  // (2,1024,512)
    const float* ln_g   = (const float*)d_in[12];
    const float* ln_b   = (const float*)d_in[13];
    const float* W_h1   = (const float*)d_in[14];
    const float* b_h1   = (const float*)d_in[15];
    const float* W_h2   = (const float*)d_in[16];
    const float* b_h2   = (const float*)d_in[17];
    float* out = (float*)d_out;

    // Workspace layout
    char* p = (char*)d_ws;
    auto alloc = [&](size_t bytes) { char* q = p; p += (bytes + 255) & ~(size_t)255; return q; };
    float*          h       = (float*)         alloc((size_t)kBT * kDMODEL * 4);
    __hip_bfloat16* h_bf    = (__hip_bfloat16*)alloc((size_t)kBT * kDMODEL * 2);
    __hip_bfloat16* xb_bf   = (__hip_bfloat16*)alloc((size_t)kBT * kDINNER * 2);
    __hip_bfloat16* z_bf    = (__hip_bfloat16*)alloc((size_t)kBT * kDINNER * 2);
    __hip_bfloat16* xc_bf   = (__hip_bfloat16*)alloc((size_t)kBT * kDINNER * 2);
    float*          xdb     = (float*)         alloc((size_t)kBT * kXPAD * 4);
    __hip_bfloat16* xdb_bf  = (__hip_bfloat16*)alloc((size_t)kBT * kXPAD * 2);
    float*          dtb     = (float*)         alloc((size_t)kBT * kDINNER * 4);
    __hip_bfloat16* ys_bf   = (__hip_bfloat16*)alloc((size_t)kBT * kDINNER * 2);
    __hip_bfloat16* wxz_bt  = (__hip_bfloat16*)alloc((size_t)2 * 2048 * 512 * 2);
    __hip_bfloat16* wxp_bt  = (__hip_bfloat16*)alloc((size_t)2 * 256 * 1024 * 2);
    __hip_bfloat16* wdt_bt  = (__hip_bfloat16*)alloc((size_t)2 * 1024 * 64 * 2);
    __hip_bfloat16* wout_bt = (__hip_bfloat16*)alloc((size_t)2 * 512 * 1024 * 2);
    float*          lnb     = (float*)         alloc(kB * kDMODEL * 4);
    float*          hid     = (float*)         alloc(kB * kDMODEL * 4);

    // Weight transposes for BOTH layers, hoisted (batched over blockIdx.z)
    wtrans_kernel<<<dim3(64, 16, 2), 256, 0, stream>>>(W_xz, 512,  2048, 512 * 2048, wxz_bt,  512,  2048 * 512);
    wtrans_kernel<<<dim3(8,  32, 2), 256, 0, stream>>>(W_xp, 1024, 160,  1024 * 160, wxp_bt,  1024, 256 * 1024);
    wtrans_kernel<<<dim3(32, 2,  2), 256, 0, stream>>>(W_dt, 32,   1024, 32 * 1024,  wdt_bt,  64,   1024 * 64);
    wtrans_kernel<<<dim3(16, 32, 2), 256, 0, stream>>>(W_out, 1024, 512, 1024 * 512, wout_bt, 1024, 512 * 1024);

    // Input projection
    in_proj_kernel<<<(kBT * kDMODEL) / 256, 256, 0, stream>>>(x, W_in, b_in, h, h_bf);

    for (int l = 0; l < kNLAYER; ++l) {
        const float* cw_l  = conv_w + (size_t)l * kDINNER * 4;
        const float* cb_l  = conv_b + (size_t)l * kDINNER;
        const float* bdt_l = b_dt   + (size_t)l * kDINNER;
        const float* Al_l  = A_log  + (size_t)l * kDINNER * kDSTATE;
        const float* Dsk_l = D_skip + (size_t)l * kDINNER;
        const __hip_bfloat16* wxz_l  = wxz_bt  + (size_t)l * 2048 * 512;
        const __hip_bfloat16* wxp_l  = wxp_bt  + (size_t)l * 256 * 1024;
        const __hip_bfloat16* wdt_l  = wdt_bt  + (size_t)l * 1024 * 64;
        const __hip_bfloat16* wout_l = wout_bt + (size_t)l * 512 * 1024;

        // xz = h @ W_xz : xb (bf16) + z (silu, bf16)
        mfma_gemm_bt<4><<<dim3(16, 32), 256, 0, stream>>>(
            h_bf, kDMODEL, wxz_l, 512, nullptr, (float*)xb_bf, kDINNER, z_bf, kDMODEL);
        // conv -> xc (bf16)
        conv_silu_kernel<<<(kBT * kDINNER) / 256, 256, 0, stream>>>(xb_bf, cw_l, cb_l, xc_bf);
        // xdb = xc @ W_xproj  (f32 + bf16, ldc=256 padded)
        mfma_gemm_bt<1><<<dim3(2, 32), 256, 0, stream>>>(
            xc_bf, kDINNER, wxp_l, 1024, nullptr, xdb, kXPAD, xdb_bf, kDINNER);
        // dt = softplus(xdb[:, :32] @ W_dt + b_dt)   (K padded to 64)
        mfma_gemm_bt<2><<<dim3(8, 32), 256, 0, stream>>>(
            xdb_bf, kXPAD, wdt_l, 64, bdt_l, dtb, kDINNER, nullptr, 64);
        // scan + gate -> ys (bf16)
        scan_kernel<<<kB * kDINNER / 4, 256, 0, stream>>>(
            dtb, xdb, xc_bf, z_bf, Al_l, Dsk_l, ys_bf);
        // h = ys @ W_out  (f32 + bf16)
        mfma_gemm_bt<1><<<dim3(4, 32), 256, 0, stream>>>(
            ys_bf, kDINNER, wout_l, 1024, nullptr, h, kDMODEL, h_bf, kDINNER);
    }

    // Tail: LN on last tokens + 2-layer head (K-unrolled f32)
    ln_last_kernel<<<kB, 256, 0, stream>>>(h, ln_g, ln_b, lnb);
    head_gemm<kDMODEL, kDMODEL, 3><<<kDMODEL / 64, 256, 0, stream>>>(lnb, W_h1, b_h1, hid);
    head_gemm<kHOR * kDOUT, kDMODEL, 0><<<(kHOR * kDOUT) / 64, 256, 0, stream>>>(hid, W_h2, b_h2, out);
}

// Round 7
// 512.779 us; speedup vs baseline: 9.5458x; 1.0306x over previous
//
#include <hip/hip_runtime.h>
#include <hip/hip_bf16.h>

// Problem constants
static constexpr int kB      = 4;
static constexpr int kT      = 1024;
static constexpr int kDIN    = 8;
static constexpr int kDMODEL = 512;
static constexpr int kNLAYER = 2;
static constexpr int kHOR    = 24;
static constexpr int kDOUT   = 8;
static constexpr int kDSTATE = 64;
static constexpr int kDINNER = 1024;
static constexpr int kDTRANK = 32;
static constexpr int kXPROJ  = 160;          // 32 + 64 + 64
static constexpr int kXPAD   = 256;          // padded xdb_bf row stride
static constexpr int kBT     = kB * kT;      // 4096

typedef __bf16 bf16x8 __attribute__((ext_vector_type(8)));
typedef float  f32x4  __attribute__((ext_vector_type(4)));

__device__ __forceinline__ float silu_f(float x)     { return x / (1.f + __expf(-x)); }
__device__ __forceinline__ float softplus_f(float x) { return (x > 20.f) ? x : log1pf(__expf(x)); }
__device__ __forceinline__ float gelu_f(float x)     { return 0.5f * x * (1.f + erff(x * 0.70710678118654752f)); }

// async global->LDS 16B
__device__ __forceinline__ void gld_lds16(const void* g, void* l) {
    __builtin_amdgcn_global_load_lds(
        (const __attribute__((address_space(1))) unsigned int*)g,
        (__attribute__((address_space(3))) unsigned int*)l, 16, 0, 0);
}

template<int CTRL>
__device__ __forceinline__ float dpp_mov(float v) {
    return __int_as_float(__builtin_amdgcn_update_dpp(
        0, __float_as_int(v), CTRL, 0xf, 0xf, false));
}

// ---------------------------------------------------------------------------
// Weight transpose + f32->bf16: out[n][k] = bf16(in[k][n]), zero-pad OOB.
// ---------------------------------------------------------------------------
__global__ __launch_bounds__(256) void wtrans_kernel(
    const float* __restrict__ in, int K, int N, int in_lstride,
    __hip_bfloat16* __restrict__ out, int Kpad, int out_lstride)
{
    __shared__ float tile[32][33];
    const int tid = threadIdx.x;
    const int n0 = blockIdx.x * 32;
    const int k0 = blockIdx.y * 32;
    const float* inl = in + (size_t)blockIdx.z * in_lstride;
    __hip_bfloat16* outl = out + (size_t)blockIdx.z * out_lstride;

#pragma unroll
    for (int p = 0; p < 4; ++p) {
        int idx = p * 256 + tid;
        int ki = idx >> 5, ni = idx & 31;
        float v = 0.f;
        if (k0 + ki < K && n0 + ni < N) v = inl[(size_t)(k0 + ki) * N + n0 + ni];
        tile[ki][ni] = v;
    }
    __syncthreads();
#pragma unroll
    for (int p = 0; p < 4; ++p) {
        int idx = p * 256 + tid;
        int ni = idx >> 5, ki = idx & 31;
        outl[(size_t)(n0 + ni) * Kpad + k0 + ki] = __float2bfloat16(tile[ki][ni]);
    }
}

// ---------------------------------------------------------------------------
// MFMA bf16 GEMM, B-transposed. 128x128 tile, BK=64, 4 waves (2x2).
// MODE 1: plain f32 C + bf16 C2
// MODE 2: softplus(v + bias[col]) -> f32 C
// MODE 4: XZ split, both bf16 (col<1024 -> bf16 xb ; col>=1024 -> silu -> z)
// MODE 5: xproj split: col<32 -> bf16 C2 (stride kXPAD);
//         col 32..96  -> f32 C[row*128 + 2(col-32)]   (B interleaved)
//         col 96..160 -> f32 C[row*128 + 2(col-96)+1] (C interleaved)
// ---------------------------------------------------------------------------
template<int MODE>
__global__ __launch_bounds__(256) void mfma_gemm_bt(
    const __hip_bfloat16* __restrict__ A, int lda,
    const __hip_bfloat16* __restrict__ BT, int ldb,
    const float* __restrict__ bias,
    float* __restrict__ C, int ldc,
    void* __restrict__ C2,
    int K)
{
    __shared__ __align__(16) __hip_bfloat16 sA[128][64];
    __shared__ __align__(16) __hip_bfloat16 sB[128][64];

    const int tid  = threadIdx.x;
    const int lane = tid & 63;
    const int w    = tid >> 6;
    const int wm   = w >> 1, wn = w & 1;
    const int m0   = blockIdx.y * 128;
    const int n0   = blockIdx.x * 128;

    f32x4 acc[4][4] = {};

    const int lrow = lane & 15;
    const int lk   = (lane >> 4) << 3;

    const int grow = tid >> 3;
    const int gcol = (tid & 7) * 8;
    char* ldsA = (char*)&sA[0][0] + w * 1024;
    char* ldsB = (char*)&sB[0][0] + w * 1024;

    for (int k0 = 0; k0 < K; k0 += 64) {
        __syncthreads();
#pragma unroll
        for (int p = 0; p < 4; ++p) {
            gld_lds16(A  + (size_t)(m0 + grow + p * 32) * lda + k0 + gcol, ldsA + p * 4096);
            gld_lds16(BT + (size_t)(n0 + grow + p * 32) * ldb + k0 + gcol, ldsB + p * 4096);
        }
        __syncthreads();
#pragma unroll
        for (int ks = 0; ks < 2; ++ks) {
            bf16x8 af[4], bfr[4];
#pragma unroll
            for (int i = 0; i < 4; ++i) {
                af[i]  = *reinterpret_cast<const bf16x8*>(&sA[wm * 64 + i * 16 + lrow][ks * 32 + lk]);
                bfr[i] = *reinterpret_cast<const bf16x8*>(&sB[wn * 64 + i * 16 + lrow][ks * 32 + lk]);
            }
#pragma unroll
            for (int i = 0; i < 4; ++i)
#pragma unroll
                for (int j = 0; j < 4; ++j)
                    acc[i][j] = __builtin_amdgcn_mfma_f32_16x16x32_bf16(af[i], bfr[j], acc[i][j], 0, 0, 0);
        }
    }

    const int crow = (lane >> 4) * 4;
    const int ccol = lane & 15;
#pragma unroll
    for (int i = 0; i < 4; ++i) {
#pragma unroll
        for (int j = 0; j < 4; ++j) {
#pragma unroll
            for (int r = 0; r < 4; ++r) {
                int row = m0 + wm * 64 + i * 16 + crow + r;
                int col = n0 + wn * 64 + j * 16 + ccol;
                float v = acc[i][j][r];
                if (MODE == 1) {
                    C[(size_t)row * ldc + col] = v;
                    ((__hip_bfloat16*)C2)[(size_t)row * ldc + col] = __float2bfloat16(v);
                } else if (MODE == 2) {
                    C[(size_t)row * ldc + col] = softplus_f(v + bias[col]);
                } else if (MODE == 4) {
                    if (col < kDINNER)
                        ((__hip_bfloat16*)C)[(size_t)row * ldc + col] = __float2bfloat16(v);
                    else
                        ((__hip_bfloat16*)C2)[(size_t)row * ldc + (col - kDINNER)] =
                            __float2bfloat16(silu_f(v));
                } else {  // MODE 5
                    if (col < kDTRANK)
                        ((__hip_bfloat16*)C2)[(size_t)row * kXPAD + col] = __float2bfloat16(v);
                    else if (col < kDTRANK + kDSTATE)
                        C[(size_t)row * 128 + (col - kDTRANK) * 2] = v;
                    else if (col < kXPROJ)
                        C[(size_t)row * 128 + (col - kDTRANK - kDSTATE) * 2 + 1] = v;
                }
            }
        }
    }
}

// ---------------------------------------------------------------------------
// Input projection: h = x @ W_in + b_in  (K=8), 4 outputs/thread.
// ---------------------------------------------------------------------------
__global__ __launch_bounds__(256) void in_proj_kernel(
    const float* __restrict__ x, const float* __restrict__ W,
    const float* __restrict__ b,
    float* __restrict__ h, __hip_bfloat16* __restrict__ hb)
{
    int idx = blockIdx.x * 256 + threadIdx.x;     // over BT*128
    int n4 = (idx & 127) * 4;
    int m  = idx >> 7;
    float4 acc = *reinterpret_cast<const float4*>(b + n4);
    const float* xr = x + m * kDIN;
#pragma unroll
    for (int k = 0; k < kDIN; ++k) {
        float4 wv = *reinterpret_cast<const float4*>(W + k * kDMODEL + n4);
        float xv = xr[k];
        acc.x = fmaf(xv, wv.x, acc.x);
        acc.y = fmaf(xv, wv.y, acc.y);
        acc.z = fmaf(xv, wv.z, acc.z);
        acc.w = fmaf(xv, wv.w, acc.w);
    }
    *reinterpret_cast<float4*>(h + (size_t)m * kDMODEL + n4) = acc;
    __bf16 o4[4] = {(__bf16)acc.x, (__bf16)acc.y, (__bf16)acc.z, (__bf16)acc.w};
    *reinterpret_cast<ushort4*>(hb + (size_t)m * kDMODEL + n4) =
        *reinterpret_cast<ushort4*>(o4);
}

// ---------------------------------------------------------------------------
// Depthwise causal conv (width 4) + bias + SiLU. 8 channels/thread, bf16x8 IO.
// ---------------------------------------------------------------------------
__global__ __launch_bounds__(256) void conv_silu_kernel(
    const __hip_bfloat16* __restrict__ xb,
    const float* __restrict__ cw, const float* __restrict__ cb,
    __hip_bfloat16* __restrict__ xc)
{
    int idx = blockIdx.x * 256 + threadIdx.x;      // over BT*128
    int dg  = (idx & 127) * 8;
    int bt  = idx >> 7;
    int t   = bt & (kT - 1);

    float4 wv[8];
#pragma unroll
    for (int k = 0; k < 8; ++k)
        wv[k] = *reinterpret_cast<const float4*>(cw + (dg + k) * 4);

    float acc[8];
#pragma unroll
    for (int k = 0; k < 8; ++k) acc[k] = cb[dg + k];

    const __hip_bfloat16* base = xb + (size_t)bt * kDINNER + dg;
    // tap sh reads row bt-sh, weight index 3-sh
    {
        bf16x8 v = *reinterpret_cast<const bf16x8*>(base);
#pragma unroll
        for (int k = 0; k < 8; ++k) acc[k] = fmaf((float)v[k], wv[k].w, acc[k]);
    }
    if (t >= 1) {
        bf16x8 v = *reinterpret_cast<const bf16x8*>(base - kDINNER);
#pragma unroll
        for (int k = 0; k < 8; ++k) acc[k] = fmaf((float)v[k], wv[k].z, acc[k]);
    }
    if (t >= 2) {
        bf16x8 v = *reinterpret_cast<const bf16x8*>(base - 2 * kDINNER);
#pragma unroll
        for (int k = 0; k < 8; ++k) acc[k] = fmaf((float)v[k], wv[k].y, acc[k]);
    }
    if (t >= 3) {
        bf16x8 v = *reinterpret_cast<const bf16x8*>(base - 3 * kDINNER);
#pragma unroll
        for (int k = 0; k < 8; ++k) acc[k] = fmaf((float)v[k], wv[k].x, acc[k]);
    }
    bf16x8 o;
#pragma unroll
    for (int k = 0; k < 8; ++k) o[k] = (__bf16)silu_f(acc[k]);
    *reinterpret_cast<bf16x8*>(xc + (size_t)bt * kDINNER + dg) = o;
}

// ---------------------------------------------------------------------------
// Selective scan. Block = 4 waves (channels d0..d0+3, same b); lane = state n.
// XCD remap: batch b owns an XCD pair -> B/C panel L2-resident.
// 32-step chunks double-buffered: (B,C) interleaved pairs -> 1 ds_read_b64;
// (dt, dt*xc) pairs in LDS -> 1 broadcast ds_read_b64 (async-split staged).
// Select+shuffle tree; direct masked epilogue store with prefetched xc/zs.
// ---------------------------------------------------------------------------
__global__ __launch_bounds__(256, 4) void scan_kernel(
    const float* __restrict__ dt,            // (bt,1024) f32
    const float* __restrict__ xdbi,          // (bt,128) f32 interleaved (B,C)
    const __hip_bfloat16* __restrict__ xc,   // (bt,1024)
    const __hip_bfloat16* __restrict__ zs,   // (bt,1024) silu(z)
    const float* __restrict__ Alog,          // (1024,64)
    const float* __restrict__ Dsk,           // (1024,)
    __hip_bfloat16* __restrict__ yg)         // (bt,1024)
{
    __shared__ __align__(16) float sBC[2][32][128];
    __shared__ __align__(8)  float sDT[2][32][4][2];

    const int tid  = threadIdx.x;
    const int lane = tid & 63;
    const int w    = tid >> 6;
    const int bb = blockIdx.x;
    const int b  = (bb & 7) >> 1;
    const int d0 = ((bb >> 3) + (bb & 1) * 128) * 4;
    const int d  = d0 + w;

    const float a2  = -__expf(Alog[d * kDSTATE + lane]) * 1.44269504f;
    const float dsk = Dsk[d];
    const size_t rowbase = (size_t)b * kT;
    float s = 0.f;

    auto stageBC = [&](int c, int buf) {
        const float* src = xdbi + (rowbase + c * 32 + w * 8 + (lane >> 5)) * 128
                                + (lane & 31) * 4;
#pragma unroll
        for (int p = 0; p < 4; ++p)
            gld_lds16(src + p * 2 * 128, &sBC[buf][w * 8 + p * 2][0]);
    };
    const int sr = (tid & 127) >> 2, sj = tid & 3;
    auto loadDT = [&](int c, float& odt, float& odx) {
        if (tid < 128) {
            size_t g = (rowbase + c * 32 + sr) * kDINNER + d0 + sj;
            odt = dt[g];
            odx = odt * (float)((const __bf16*)xc)[g];
        }
    };
    auto writeDT = [&](int buf, float vdt, float vdx) {
        if (tid < 128) {
            sDT[buf][sr][sj][0] = vdt;
            sDT[buf][sr][sj][1] = vdx;
        }
    };
    auto loadEP = [&](int c, float& oxv, float& ozv) {
        size_t g = (rowbase + c * 32 + (lane & 31)) * kDINNER + d;
        oxv = (float)((const __bf16*)xc)[g];
        ozv = (float)((const __bf16*)zs)[g];
    };

    float pdt = 0.f, pdx = 0.f, exv = 0.f, ezv = 0.f;
    stageBC(0, 0);
    loadDT(0, pdt, pdx);
    loadEP(0, exv, ezv);
    writeDT(0, pdt, pdx);
    __syncthreads();

    for (int c = 0; c < kT / 32; ++c) {
        const int buf = c & 1;
        float ndt = 0.f, ndx = 0.f, nxv = 0.f, nzv = 0.f;
        const bool more = (c + 1 < kT / 32);
        if (more) {
            stageBC(c + 1, buf ^ 1);
            loadDT(c + 1, ndt, ndx);
            loadEP(c + 1, nxv, nzv);
        }

        // recurrence: per-lane y partials for 32 steps
        float yv[32];
#pragma unroll
        for (int i = 0; i < 32; ++i) {
            float2 bc = *reinterpret_cast<const float2*>(&sBC[buf][i][lane * 2]);
            float2 dd = *reinterpret_cast<const float2*>(&sDT[buf][i][w][0]);
            float dA = exp2f(dd.x * a2);
            s = fmaf(dA, s, dd.y * bc.x);
            yv[i] = s * bc.y;
        }

        // transpose-reduce: lane L -> full sum of step (L&31)
#pragma unroll
        for (int m = 0; m < 16; ++m) {
            float av = yv[2 * m], bv = yv[2 * m + 1];
            float cv = (lane & 1) ? bv : av;
            float dv = (lane & 1) ? av : bv;
            yv[m] = cv + dpp_mov<0xB1>(dv);     // quad_perm [1,0,3,2]
        }
#pragma unroll
        for (int m = 0; m < 8; ++m) {
            float av = yv[2 * m], bv = yv[2 * m + 1];
            float cv = (lane & 2) ? bv : av;
            float dv = (lane & 2) ? av : bv;
            yv[m] = cv + dpp_mov<0x4E>(dv);     // quad_perm [2,3,0,1]
        }
#pragma unroll
        for (int j = 2; j < 5; ++j) {
            const int S = 1 << j;
#pragma unroll
            for (int m = 0; m < (32 >> (j + 1)); ++m) {
                float av = yv[2 * m], bv = yv[2 * m + 1];
                float cv = (lane & S) ? bv : av;
                float dv = (lane & S) ? av : bv;
                yv[m] = cv + __shfl_xor(dv, S, 64);
            }
        }
        float y = yv[0];
        y += __shfl_xor(y, 32, 64);

        // epilogue: all lanes hold y/xv/zv for step lane&31; store from half 0
        float yo = fmaf(dsk, exv, y) * ezv;
        if (lane < 32) {
            size_t g = (rowbase + c * 32 + lane) * kDINNER + d;
            yg[g] = __float2bfloat16(yo);
        }
        if (more) writeDT(buf ^ 1, ndt, ndx);
        __syncthreads();
        exv = nxv; ezv = nzv;
    }
}

// ---------------------------------------------------------------------------
// Head GEMM: C[b][n] = act(sum_k A[b][k]*B[k][n] + bias[n]), b=0..3.
// ---------------------------------------------------------------------------
template<int N, int KK, int ACT>
__global__ __launch_bounds__(256) void head_gemm(
    const float* __restrict__ A,
    const float* __restrict__ B,
    const float* __restrict__ bias,
    float* __restrict__ C)
{
    const int n = blockIdx.x * 64 + (threadIdx.x & 63);
    const int b = threadIdx.x >> 6;
    const float* a  = A + b * KK;
    const float* bp = B + n;
    float acc = 0.f;
#pragma unroll 16
    for (int k = 0; k < KK; ++k)
        acc = fmaf(a[k], bp[(size_t)k * N], acc);
    float v = acc + bias[n];
    if (ACT == 3) v = gelu_f(v);
    C[(size_t)b * N + n] = v;
}

// ---------------------------------------------------------------------------
// LayerNorm of the 4 last-token rows only.
// ---------------------------------------------------------------------------
__global__ __launch_bounds__(256) void ln_last_kernel(
    const float* __restrict__ h,
    const float* __restrict__ g, const float* __restrict__ be,
    float* __restrict__ out)
{
    __shared__ float sbuf[8];
    int b = blockIdx.x, tid = threadIdx.x;
    const float* row = h + (size_t)(b * kT + (kT - 1)) * kDMODEL;

    float v0 = row[tid], v1 = row[tid + 256];
    float s = v0 + v1;
    float q = v0 * v0 + v1 * v1;
#pragma unroll
    for (int m = 32; m >= 1; m >>= 1) {
        s += __shfl_xor(s, m, 64);
        q += __shfl_xor(q, m, 64);
    }
    int wid = tid >> 6;
    if ((tid & 63) == 0) { sbuf[wid] = s; sbuf[4 + wid] = q; }
    __syncthreads();
    if (tid == 0) {
        float S = 0.f, Q = 0.f;
        for (int i = 0; i < 4; ++i) { S += sbuf[i]; Q += sbuf[4 + i]; }
        sbuf[0] = S; sbuf[4] = Q;
    }
    __syncthreads();
    float mean = sbuf[0] * (1.f / kDMODEL);
    float var  = sbuf[4] * (1.f / kDMODEL) - mean * mean;
    float inv  = rsqrtf(var + 1e-5f);
    out[b * kDMODEL + tid]       = (v0 - mean) * inv * g[tid]       + be[tid];
    out[b * kDMODEL + tid + 256] = (v1 - mean) * inv * g[tid + 256] + be[tid + 256];
}

// ---------------------------------------------------------------------------
extern "C" void kernel_launch(void* const* d_in, const int* in_sizes, int n_in,
                              void* d_out, int out_size, void* d_ws, size_t ws_size,
                              hipStream_t stream)
{
    const float* x      = (const float*)d_in[0];
    const float* W_in   = (const float*)d_in[1];
    const float* b_in   = (const float*)d_in[2];
    const float* W_xz   = (const float*)d_in[3];   // (2,512,2048)
    const float* conv_w = (const float*)d_in[4];
    const float* conv_b = (const float*)d_in[5];
    const float* W_xp   = (const float*)d_in[6];   // (2,1024,160)
    const float* W_dt   = (const float*)d_in[7];   // (2,32,1024)
    const float* b_dt   = (const float*)d_in[8];
    const float* A_log  = (const float*)d_in[9];
    const float* D_skip = (const float*)d_in[10];
    const float* W_out  = (const float*)d_in[11];  // (2,1024,512)
    const float* ln_g   = (const float*)d_in[12];
    const float* ln_b   = (const float*)d_in[13];
    const float* W_h1   = (const float*)d_in[14];
    const float* b_h1   = (const float*)d_in[15];
    const float* W_h2   = (const float*)d_in[16];
    const float* b_h2   = (const float*)d_in[17];
    float* out = (float*)d_out;

    // Workspace layout
    char* p = (char*)d_ws;
    auto alloc = [&](size_t bytes) { char* q = p; p += (bytes + 255) & ~(size_t)255; return q; };
    float*          h       = (float*)         alloc((size_t)kBT * kDMODEL * 4);
    __hip_bfloat16* h_bf    = (__hip_bfloat16*)alloc((size_t)kBT * kDMODEL * 2);
    __hip_bfloat16* xb_bf   = (__hip_bfloat16*)alloc((size_t)kBT * kDINNER * 2);
    __hip_bfloat16* z_bf    = (__hip_bfloat16*)alloc((size_t)kBT * kDINNER * 2);
    __hip_bfloat16* xc_bf   = (__hip_bfloat16*)alloc((size_t)kBT * kDINNER * 2);
    float*          xdbi    = (float*)         alloc((size_t)kBT * 128 * 4);
    __hip_bfloat16* xdb_bf  = (__hip_bfloat16*)alloc((size_t)kBT * kXPAD * 2);
    float*          dtb     = (float*)         alloc((size_t)kBT * kDINNER * 4);
    __hip_bfloat16* ys_bf   = (__hip_bfloat16*)alloc((size_t)kBT * kDINNER * 2);
    __hip_bfloat16* wxz_bt  = (__hip_bfloat16*)alloc((size_t)2 * 2048 * 512 * 2);
    __hip_bfloat16* wxp_bt  = (__hip_bfloat16*)alloc((size_t)2 * 256 * 1024 * 2);
    __hip_bfloat16* wdt_bt  = (__hip_bfloat16*)alloc((size_t)2 * 1024 * 64 * 2);
    __hip_bfloat16* wout_bt = (__hip_bfloat16*)alloc((size_t)2 * 512 * 1024 * 2);
    float*          lnb     = (float*)         alloc(kB * kDMODEL * 4);
    float*          hid     = (float*)         alloc(kB * kDMODEL * 4);

    // Weight transposes for BOTH layers, hoisted (batched over blockIdx.z)
    wtrans_kernel<<<dim3(64, 16, 2), 256, 0, stream>>>(W_xz, 512,  2048, 512 * 2048, wxz_bt,  512,  2048 * 512);
    wtrans_kernel<<<dim3(8,  32, 2), 256, 0, stream>>>(W_xp, 1024, 160,  1024 * 160, wxp_bt,  1024, 256 * 1024);
    wtrans_kernel<<<dim3(32, 2,  2), 256, 0, stream>>>(W_dt, 32,   1024, 32 * 1024,  wdt_bt,  64,   1024 * 64);
    wtrans_kernel<<<dim3(16, 32, 2), 256, 0, stream>>>(W_out, 1024, 512, 1024 * 512, wout_bt, 1024, 512 * 1024);

    // Input projection (4 outputs/thread)
    in_proj_kernel<<<(kBT * 128) / 256, 256, 0, stream>>>(x, W_in, b_in, h, h_bf);

    for (int l = 0; l < kNLAYER; ++l) {
        const float* cw_l  = conv_w + (size_t)l * kDINNER * 4;
        const float* cb_l  = conv_b + (size_t)l * kDINNER;
        const float* bdt_l = b_dt   + (size_t)l * kDINNER;
        const float* Al_l  = A_log  + (size_t)l * kDINNER * kDSTATE;
        const float* Dsk_l = D_skip + (size_t)l * kDINNER;
        const __hip_bfloat16* wxz_l  = wxz_bt  + (size_t)l * 2048 * 512;
        const __hip_bfloat16* wxp_l  = wxp_bt  + (size_t)l * 256 * 1024;
        const __hip_bfloat16* wdt_l  = wdt_bt  + (size_t)l * 1024 * 64;
        const __hip_bfloat16* wout_l = wout_bt + (size_t)l * 512 * 1024;

        // xz = h @ W_xz : xb (bf16) + z (silu, bf16)
        mfma_gemm_bt<4><<<dim3(16, 32), 256, 0, stream>>>(
            h_bf, kDMODEL, wxz_l, 512, nullptr, (float*)xb_bf, kDINNER, z_bf, kDMODEL);
        // conv -> xc (bf16), 8 channels/thread
        conv_silu_kernel<<<(kBT * 128) / 256, 256, 0, stream>>>(xb_bf, cw_l, cb_l, xc_bf);
        // xdb = xc @ W_xproj : dt-rank -> xdb_bf ; B,C -> interleaved xdbi
        mfma_gemm_bt<5><<<dim3(2, 32), 256, 0, stream>>>(
            xc_bf, kDINNER, wxp_l, 1024, nullptr, xdbi, 128, xdb_bf, kDINNER);
        // dt = softplus(xdb[:, :32] @ W_dt + b_dt)   (K padded to 64)
        mfma_gemm_bt<2><<<dim3(8, 32), 256, 0, stream>>>(
            xdb_bf, kXPAD, wdt_l, 64, bdt_l, dtb, kDINNER, nullptr, 64);
        // scan + gate -> ys (bf16)
        scan_kernel<<<kB * kDINNER / 4, 256, 0, stream>>>(
            dtb, xdbi, xc_bf, z_bf, Al_l, Dsk_l, ys_bf);
        // h = ys @ W_out  (f32 + bf16)
        mfma_gemm_bt<1><<<dim3(4, 32), 256, 0, stream>>>(
            ys_bf, kDINNER, wout_l, 1024, nullptr, h, kDMODEL, h_bf, kDINNER);
    }

    // Tail: LN on last tokens + 2-layer head (K-unrolled f32)
    ln_last_kernel<<<kB, 256, 0, stream>>>(h, ln_g, ln_b, lnb);
    head_gemm<kDMODEL, kDMODEL, 3><<<kDMODEL / 64, 256, 0, stream>>>(lnb, W_h1, b_h1, hid);
    head_gemm<kHOR * kDOUT, kDMODEL, 0><<<(kHOR * kDOUT) / 64, 256, 0, stream>>>(hid, W_h2, b_h2, out);
}